// Round 2
// baseline (7464.938 us; speedup 1.0000x reference)
//
#include <hip/hip_runtime.h>

constexpr int DIN = 128, HIDF = 8, OUTF = 7;

// ---------------- layer-1 projection: xp[N,8] = x[N,128] @ w[128,8] + b ----------------
__global__ __launch_bounds__(256) void k_proj1(
    const float* __restrict__ x, const float* __restrict__ w,
    const float* __restrict__ b, float* __restrict__ xp, int N)
{
  __shared__ float ws_[DIN * HIDF];   // 1024 floats
  __shared__ float xs[32 * 132];      // 32 rows, padded stride 132
  int t = threadIdx.x;
  ((float4*)ws_)[t] = ((const float4*)w)[t];  // 256 * 16B = 4KB
  int base = blockIdx.x * 32;
#pragma unroll
  for (int i = 0; i < 4; i++) {
    int f4 = t + i * 256;            // 0..1023 float4s = 32 rows * 128 floats
    int nl = f4 >> 5;
    if (base + nl < N) {
      float4 v = ((const float4*)(x + (size_t)base * DIN))[f4];
      int col = (f4 & 31) << 2;
      *((float4*)&xs[nl * 132 + col]) = v;
    }
  }
  __syncthreads();
  int nl = t >> 3, j = t & 7;
  int n0 = base + nl;
  if (n0 >= N) return;
  float acc = b[j];
  const float* xr = &xs[nl * 132];
#pragma unroll 8
  for (int k = 0; k < DIN; k++) acc = fmaf(xr[k], ws_[k * HIDF + j], acc);
  xp[(size_t)n0 * HIDF + j] = acc;
}

// ---------------- per-node attention coefficients, layer 1 (H=2, D=4) ----------------
__global__ __launch_bounds__(256) void k_alpha1(
    const float* __restrict__ xp, int N,
    const float* __restrict__ p0, float* __restrict__ o0,
    const float* __restrict__ p1, float* __restrict__ o1,
    const float* __restrict__ p2, float* __restrict__ o2,
    const float* __restrict__ p3, float* __restrict__ o3)
{
  int n = blockIdx.x * blockDim.x + threadIdx.x;
  if (n >= N) return;
  float4 a4 = ((const float4*)xp)[n * 2];
  float4 b4 = ((const float4*)xp)[n * 2 + 1];
  float xv[8] = {a4.x, a4.y, a4.z, a4.w, b4.x, b4.y, b4.z, b4.w};
#define DOA(p, o)                                                     \
  if (p) {                                                            \
    float s0 = 0.f, s1 = 0.f;                                         \
    for (int d = 0; d < 4; d++) { s0 += xv[d] * p[d]; s1 += xv[4 + d] * p[4 + d]; } \
    ((float2*)o)[n] = make_float2(s0, s1);                            \
  }
  DOA(p0, o0) DOA(p1, o1) DOA(p2, o2) DOA(p3, o3)
#undef DOA
}

// ---------------- edge pass, layer 1: accumulate exp(lrelu(a)) and exp*xsrc ----------------
__global__ __launch_bounds__(256) void k_edge1(
    const int* __restrict__ src, const int* __restrict__ dst,
    const float* __restrict__ as_, const float* __restrict__ ad_,
    const float* __restrict__ xps, float* __restrict__ sden,
    float* __restrict__ o, int E)
{
  int e = blockIdx.x * blockDim.x + threadIdx.x;
  if (e >= E) return;
  int s = src[e], d = dst[e];
  float2 av = ((const float2*)as_)[s];
  float2 dv = ((const float2*)ad_)[d];
  float a0 = av.x + dv.x; a0 = a0 > 0.f ? a0 : 0.2f * a0;
  float a1 = av.y + dv.y; a1 = a1 > 0.f ? a1 : 0.2f * a1;
  float e0 = __expf(a0), e1 = __expf(a1);
  atomicAdd(&sden[(size_t)d * 2 + 0], e0);
  atomicAdd(&sden[(size_t)d * 2 + 1], e1);
  float4 x0 = ((const float4*)xps)[s * 2];
  float4 x1 = ((const float4*)xps)[s * 2 + 1];
  float* ob = o + (size_t)d * 8;
  atomicAdd(ob + 0, e0 * x0.x); atomicAdd(ob + 1, e0 * x0.y);
  atomicAdd(ob + 2, e0 * x0.z); atomicAdd(ob + 3, e0 * x0.w);
  atomicAdd(ob + 4, e1 * x1.x); atomicAdd(ob + 5, e1 * x1.y);
  atomicAdd(ob + 6, e1 * x1.z); atomicAdd(ob + 7, e1 * x1.w);
}

// ---------------- normalize + relu, layer 1 ----------------
__global__ __launch_bounds__(256) void k_fin1(float* __restrict__ o,
                                              const float* __restrict__ sden, int N)
{
  int i = blockIdx.x * blockDim.x + threadIdx.x;
  if (i >= N * 8) return;
  int n = i >> 3, f = i & 7;
  float s = sden[n * 2 + (f >> 2)] + 1e-16f;
  float v = o[i] / s;
  o[i] = v > 0.f ? v : 0.f;
}

// ---------------- semantic-attention reduction: red[f] += sum_n tanh(h[n]@kw+kb)[f] ----------------
__global__ __launch_bounds__(256) void k_red(
    const float* __restrict__ h, int N, int F,
    const float* __restrict__ kw, const float* __restrict__ kb,
    float* __restrict__ red)
{
  __shared__ float kws[64], kbs[8];
  __shared__ float sm[256 * 8];
  int t = threadIdx.x;
  if (t < F * F) kws[t] = kw[t];
  if (t < F) kbs[t] = kb[t];
  __syncthreads();
  float acc[8] = {0, 0, 0, 0, 0, 0, 0, 0};
  for (int n = blockIdx.x * 256 + t; n < N; n += gridDim.x * 256) {
    const float* row = h + (size_t)n * 8;
    float xv[8];
    for (int k = 0; k < F; k++) xv[k] = row[k];
    for (int f = 0; f < F; f++) {
      float s = kbs[f];
      for (int k = 0; k < F; k++) s += xv[k] * kws[k * F + f];
      acc[f] += tanhf(s);
    }
  }
  for (int f = 0; f < 8; f++) sm[t * 8 + f] = (f < F) ? acc[f] : 0.f;
  __syncthreads();
  for (int s2 = 128; s2 > 0; s2 >>= 1) {
    if (t < s2)
      for (int f = 0; f < 8; f++) sm[t * 8 + f] += sm[(t + s2) * 8 + f];
    __syncthreads();
  }
  if (t < F) atomicAdd(&red[t], sm[t]);
}

// ---------------- semantic attention weights (tiny) ----------------
__global__ void k_attn(const float* __restrict__ red, const float* __restrict__ q,
                       int T, int F, float invN, float* __restrict__ attn)
{
  if (threadIdx.x != 0 || blockIdx.x != 0) return;
  float v[4]; float m = -1e30f;
  for (int t2 = 0; t2 < T; t2++) {
    float s = 0.f;
    for (int f = 0; f < F; f++) s += q[f] * red[t2 * F + f];
    s *= invN;
    v[t2] = s; m = fmaxf(m, s);
  }
  float sum = 0.f;
  for (int t2 = 0; t2 < T; t2++) { v[t2] = __expf(v[t2] - m); sum += v[t2]; }
  for (int t2 = 0; t2 < T; t2++) attn[t2] = v[t2] / sum;
}

// ---------------- weighted combine (+relu, no-op but matches ref) ----------------
__global__ __launch_bounds__(256) void k_comb(
    const float* __restrict__ h0, const float* __restrict__ h1,
    const float* __restrict__ attn, float* __restrict__ out, int NF)
{
  int i = blockIdx.x * blockDim.x + threadIdx.x;
  if (i >= NF) return;
  float v = attn[0] * h0[i] + attn[1] * h1[i];
  out[i] = v > 0.f ? v : 0.f;
}

// ---------------- layer-2 projection (8->7, padded stride 8) + fused alpha2 ----------------
__global__ __launch_bounds__(256) void k_proj2(
    const float* __restrict__ xin, int N,
    const float* __restrict__ w, const float* __restrict__ b,
    float* __restrict__ xp2,
    const float* __restrict__ pa0, float* __restrict__ oa0,
    const float* __restrict__ pa1, float* __restrict__ oa1,
    const float* __restrict__ pa2, float* __restrict__ oa2)
{
  int n = blockIdx.x * blockDim.x + threadIdx.x;
  if (n >= N) return;
  float4 a4 = ((const float4*)xin)[n * 2];
  float4 b4 = ((const float4*)xin)[n * 2 + 1];
  float xv[8] = {a4.x, a4.y, a4.z, a4.w, b4.x, b4.y, b4.z, b4.w};
  float y[7];
  for (int j = 0; j < 7; j++) y[j] = b[j];
  for (int k = 0; k < 8; k++) {
    float xk = xv[k];
    for (int j = 0; j < 7; j++) y[j] += xk * w[k * 7 + j];
  }
  ((float4*)xp2)[n * 2] = make_float4(y[0], y[1], y[2], y[3]);
  ((float4*)xp2)[n * 2 + 1] = make_float4(y[4], y[5], y[6], 0.f);
#define DOA2(p, o)                                      \
  if (p) {                                              \
    float s = 0.f;                                      \
    for (int j = 0; j < 7; j++) s += y[j] * p[j];       \
    o[n] = s;                                           \
  }
  DOA2(pa0, oa0) DOA2(pa1, oa1) DOA2(pa2, oa2)
#undef DOA2
}

// ---------------- edge pass, layer 2 (H=1, F=7, padded 8) ----------------
__global__ __launch_bounds__(256) void k_edge2(
    const int* __restrict__ src, const int* __restrict__ dst,
    const float* __restrict__ as_, const float* __restrict__ ad_,
    const float* __restrict__ xps, float* __restrict__ sden,
    float* __restrict__ o, int E)
{
  int e = blockIdx.x * blockDim.x + threadIdx.x;
  if (e >= E) return;
  int s = src[e], d = dst[e];
  float a = as_[s] + ad_[d]; a = a > 0.f ? a : 0.2f * a;
  float ex = __expf(a);
  atomicAdd(&sden[d], ex);
  float4 x0 = ((const float4*)xps)[s * 2];
  float4 x1 = ((const float4*)xps)[s * 2 + 1];
  float* ob = o + (size_t)d * 8;
  atomicAdd(ob + 0, ex * x0.x); atomicAdd(ob + 1, ex * x0.y);
  atomicAdd(ob + 2, ex * x0.z); atomicAdd(ob + 3, ex * x0.w);
  atomicAdd(ob + 4, ex * x1.x); atomicAdd(ob + 5, ex * x1.y);
  atomicAdd(ob + 6, ex * x1.z);
}

// ---------------- normalize + relu, layer 2 ----------------
__global__ __launch_bounds__(256) void k_fin2(float* __restrict__ o,
                                              const float* __restrict__ sden, int N)
{
  int n = blockIdx.x * blockDim.x + threadIdx.x;
  if (n >= N) return;
  float s = sden[n] + 1e-16f;
  float* r = o + (size_t)n * 8;
  for (int c = 0; c < 7; c++) { float v = r[c] / s; r[c] = v > 0.f ? v : 0.f; }
}

// ---------------- final combine + log_softmax ----------------
__global__ __launch_bounds__(256) void k_final(
    const float* __restrict__ h0, const float* __restrict__ h1,
    const float* __restrict__ attn, float* __restrict__ out, int N)
{
  int n = blockIdx.x * blockDim.x + threadIdx.x;
  if (n >= N) return;
  float a0 = attn[0], a1 = attn[1];
  const float* r0 = h0 + (size_t)n * 8;
  const float* r1 = h1 + (size_t)n * 8;
  float v[7]; float m = -1e30f;
  for (int c = 0; c < 7; c++) { float t = a0 * r0[c] + a1 * r1[c]; v[c] = t; m = fmaxf(m, t); }
  float sum = 0.f;
  for (int c = 0; c < 7; c++) sum += __expf(v[c] - m);
  float lse = m + logf(sum);
  for (int c = 0; c < 7; c++) out[(size_t)n * 7 + c] = v[c] - lse;
}

extern "C" void kernel_launch(void* const* d_in, const int* in_sizes, int n_in,
                              void* d_out, int out_size, void* d_ws, size_t ws_size,
                              hipStream_t stream)
{
  const float* x_p  = (const float*)d_in[0];
  const float* x_a  = (const float*)d_in[1];
  const int*   eipp = (const int*)d_in[2];
  const int*   eipa = (const int*)d_in[3];
  const int*   eiap = (const int*)d_in[4];
  const float* w1p  = (const float*)d_in[5];
  const float* b1p  = (const float*)d_in[6];
  const float* w1a  = (const float*)d_in[7];
  const float* b1a  = (const float*)d_in[8];
  const float* as1pp = (const float*)d_in[9];
  const float* ad1pp = (const float*)d_in[10];
  const float* as1pa = (const float*)d_in[11];
  const float* ad1pa = (const float*)d_in[12];
  const float* as1ap = (const float*)d_in[13];
  const float* ad1ap = (const float*)d_in[14];
  const float* kw1 = (const float*)d_in[15];
  const float* kb1 = (const float*)d_in[16];
  const float* q1  = (const float*)d_in[17];
  const float* w2p = (const float*)d_in[18];
  const float* b2p = (const float*)d_in[19];
  const float* w2a = (const float*)d_in[20];
  const float* b2a = (const float*)d_in[21];
  const float* as2pp = (const float*)d_in[22];
  const float* ad2pp = (const float*)d_in[23];
  // d_in[24]=as2pa, d_in[25]=ad2pa unused: pa edges only feed author nodes,
  // and author layer-2 output is dead (final output is papers only).
  const float* as2ap = (const float*)d_in[26];
  const float* ad2ap = (const float*)d_in[27];
  const float* kw2 = (const float*)d_in[28];
  const float* kb2 = (const float*)d_in[29];
  const float* q2  = (const float*)d_in[30];

  const int NP = in_sizes[0] / DIN;
  const int NA = in_sizes[1] / DIN;
  const int E  = in_sizes[2] / 2;
  (void)n_in; (void)out_size; (void)ws_size;

  float* w = (float*)d_ws;
  size_t off = 0;
  auto A = [&](size_t n) { float* p = w + off; off += n; return p; };
  float* XP_P1 = A((size_t)NP * 8);
  float* XP_A1 = A((size_t)NA * 8);
  float* AS_PP = A((size_t)NP * 2);
  float* AD_PP = A((size_t)NP * 2);
  float* AS_PA = A((size_t)NP * 2);
  float* AD_PA = A((size_t)NA * 2);
  float* AS_AP = A((size_t)NA * 2);
  float* AD_AP = A((size_t)NP * 2);
  float* XP2_P = A((size_t)NP * 8);
  float* XP2_A = A((size_t)NA * 8);
  float* A2SPP = A((size_t)NP);
  float* A2DPP = A((size_t)NP);
  float* A2DAP = A((size_t)NP);
  float* A2SAP = A((size_t)NA);
  float* XPAP2 = A((size_t)NP * 8);
  // ---- zero-initialized accumulator region starts here ----
  float* ACC0 = w + off;
  float* S_PP = A((size_t)NP * 2);
  float* S_PA = A((size_t)NA * 2);
  float* S_AP = A((size_t)NP * 2);
  float* O_PP = A((size_t)NP * 8);
  float* O_PA = A((size_t)NA * 8);
  float* O_AP = A((size_t)NP * 8);
  float* S2PP = A((size_t)NP);
  float* S2AP = A((size_t)NP);
  float* O2PP = A((size_t)NP * 8);
  float* O2AP = A((size_t)NP * 8);
  float* RED1 = A(16);
  float* RED2 = A(14);
  float* ATT1 = A(2);
  float* ATT2 = A(2);
  size_t accBytes = (size_t)((w + off) - ACC0) * sizeof(float);

  hipMemsetAsync(ACC0, 0, accBytes, stream);

  dim3 B(256);
  // layer 1 projections + per-node alphas
  k_proj1<<<(NP + 31) / 32, B, 0, stream>>>(x_p, w1p, b1p, XP_P1, NP);
  k_proj1<<<(NA + 31) / 32, B, 0, stream>>>(x_a, w1a, b1a, XP_A1, NA);
  k_alpha1<<<(NP + 255) / 256, B, 0, stream>>>(XP_P1, NP,
      as1pp, AS_PP, ad1pp, AD_PP, as1pa, AS_PA, ad1ap, AD_AP);
  k_alpha1<<<(NA + 255) / 256, B, 0, stream>>>(XP_A1, NA,
      ad1pa, AD_PA, as1ap, AS_AP, nullptr, nullptr, nullptr, nullptr);
  // layer 1 edge passes (single pass each: exp-without-max + fused normalize later)
  int gE = (E + 255) / 256;
  k_edge1<<<gE, B, 0, stream>>>(eipp, eipp + E, AS_PP, AD_PP, XP_P1, S_PP, O_PP, E);
  k_edge1<<<gE, B, 0, stream>>>(eipa, eipa + E, AS_PA, AD_PA, XP_P1, S_PA, O_PA, E);
  k_edge1<<<gE, B, 0, stream>>>(eiap, eiap + E, AS_AP, AD_AP, XP_A1, S_AP, O_AP, E);
  k_fin1<<<(NP * 8 + 255) / 256, B, 0, stream>>>(O_PP, S_PP, NP);
  k_fin1<<<(NA * 8 + 255) / 256, B, 0, stream>>>(O_PA, S_PA, NA);
  k_fin1<<<(NP * 8 + 255) / 256, B, 0, stream>>>(O_AP, S_AP, NP);
  // layer 1 semantic attention (paper: T=2; author: T=1 -> weight 1, use O_PA directly)
  k_red<<<256, B, 0, stream>>>(O_PP, NP, 8, kw1, kb1, RED1);
  k_red<<<256, B, 0, stream>>>(O_AP, NP, 8, kw1, kb1, RED1 + 8);
  k_attn<<<1, 1, 0, stream>>>(RED1, q1, 2, 8, 1.0f / NP, ATT1);
  k_comb<<<(NP * 8 + 255) / 256, B, 0, stream>>>(O_PP, O_AP, ATT1, XPAP2, NP * 8);
  // layer 2 projections + fused alphas
  k_proj2<<<(NP + 255) / 256, B, 0, stream>>>(XPAP2, NP, w2p, b2p, XP2_P,
      as2pp, A2SPP, ad2pp, A2DPP, ad2ap, A2DAP);
  k_proj2<<<(NA + 255) / 256, B, 0, stream>>>(O_PA, NA, w2a, b2a, XP2_A,
      as2ap, A2SAP, nullptr, nullptr, nullptr, nullptr);
  // layer 2 edge passes (pp and ap only)
  k_edge2<<<gE, B, 0, stream>>>(eipp, eipp + E, A2SPP, A2DPP, XP2_P, S2PP, O2PP, E);
  k_edge2<<<gE, B, 0, stream>>>(eiap, eiap + E, A2SAP, A2DAP, XP2_A, S2AP, O2AP, E);
  k_fin2<<<(NP + 255) / 256, B, 0, stream>>>(O2PP, S2PP, NP);
  k_fin2<<<(NP + 255) / 256, B, 0, stream>>>(O2AP, S2AP, NP);
  // layer 2 semantic attention + final log_softmax
  k_red<<<256, B, 0, stream>>>(O2PP, NP, 7, kw2, kb2, RED2);
  k_red<<<256, B, 0, stream>>>(O2AP, NP, 7, kw2, kb2, RED2 + 7);
  k_attn<<<1, 1, 0, stream>>>(RED2, q2, 2, 7, 1.0f / NP, ATT2);
  k_final<<<(NP + 255) / 256, B, 0, stream>>>(O2PP, O2AP, ATT2, (float*)d_out, NP);
}

// Round 3
// 1086.047 us; speedup vs baseline: 6.8735x; 6.8735x over previous
//
#include <hip/hip_runtime.h>

constexpr int DIN = 128, HIDF = 8, OUTF = 7;

// ---------------- layer-1 projection: xp[N,8] = x[N,128] @ w[128,8] + b ----------------
__global__ __launch_bounds__(256) void k_proj1(
    const float* __restrict__ x, const float* __restrict__ w,
    const float* __restrict__ b, float* __restrict__ xp, int N)
{
  __shared__ float ws_[DIN * HIDF];   // 1024 floats
  __shared__ float xs[32 * 132];      // 32 rows, padded stride 132
  int t = threadIdx.x;
  ((float4*)ws_)[t] = ((const float4*)w)[t];  // 256 * 16B = 4KB
  int base = blockIdx.x * 32;
#pragma unroll
  for (int i = 0; i < 4; i++) {
    int f4 = t + i * 256;            // 0..1023 float4s = 32 rows * 128 floats
    int nl = f4 >> 5;
    if (base + nl < N) {
      float4 v = ((const float4*)(x + (size_t)base * DIN))[f4];
      int col = (f4 & 31) << 2;
      *((float4*)&xs[nl * 132 + col]) = v;
    }
  }
  __syncthreads();
  int nl = t >> 3, j = t & 7;
  int n0 = base + nl;
  if (n0 >= N) return;
  float acc = b[j];
  const float* xr = &xs[nl * 132];
#pragma unroll 8
  for (int k = 0; k < DIN; k++) acc = fmaf(xr[k], ws_[k * HIDF + j], acc);
  xp[(size_t)n0 * HIDF + j] = acc;
}

// ---------------- per-node attention coefficients, layer 1 (H=2, D=4) ----------------
__global__ __launch_bounds__(256) void k_alpha1(
    const float* __restrict__ xp, int N,
    const float* __restrict__ p0, float* __restrict__ o0,
    const float* __restrict__ p1, float* __restrict__ o1,
    const float* __restrict__ p2, float* __restrict__ o2,
    const float* __restrict__ p3, float* __restrict__ o3)
{
  int n = blockIdx.x * blockDim.x + threadIdx.x;
  if (n >= N) return;
  float4 a4 = ((const float4*)xp)[n * 2];
  float4 b4 = ((const float4*)xp)[n * 2 + 1];
  float xv[8] = {a4.x, a4.y, a4.z, a4.w, b4.x, b4.y, b4.z, b4.w};
#define DOA(p, o)                                                     \
  if (p) {                                                            \
    float s0 = 0.f, s1 = 0.f;                                         \
    for (int d = 0; d < 4; d++) { s0 += xv[d] * p[d]; s1 += xv[4 + d] * p[4 + d]; } \
    ((float2*)o)[n] = make_float2(s0, s1);                            \
  }
  DOA(p0, o0) DOA(p1, o1) DOA(p2, o2) DOA(p3, o3)
#undef DOA
}

// ---------------- CSR build: histogram + rank capture (1 int atomic / edge) ----------------
__global__ __launch_bounds__(256) void k_hist(
    const int* __restrict__ dst, int E, int* __restrict__ deg, int* __restrict__ rank)
{
  int e = blockIdx.x * 256 + threadIdx.x;
  if (e >= E) return;
  rank[e] = atomicAdd(&deg[dst[e]], 1);
}

// ---------------- exclusive scan, 3-phase (N ~ 100k) ----------------
__global__ __launch_bounds__(256) void k_scan1(
    const int* __restrict__ deg, int N, int* __restrict__ off, int* __restrict__ bsum)
{
  int t = threadIdx.x;
  int i = blockIdx.x * 256 + t;
  int v = (i < N) ? deg[i] : 0;
  int lane = t & 63, w = t >> 6;
  int x = v;
#pragma unroll
  for (int o = 1; o < 64; o <<= 1) { int u = __shfl_up(x, o, 64); if (lane >= o) x += u; }
  __shared__ int ws[4];
  if (lane == 63) ws[w] = x;
  __syncthreads();
  if (t == 0) { int s = 0; for (int k = 0; k < 4; k++) { int tmp = ws[k]; ws[k] = s; s += tmp; } }
  __syncthreads();
  int excl = x - v + ws[w];
  if (i < N) off[i] = excl;
  if (t == 255) bsum[blockIdx.x] = excl + v;
}

__global__ __launch_bounds__(256) void k_scan2(int* __restrict__ b, int nb)
{
  __shared__ int ws[4];
  __shared__ int carry;
  int t = threadIdx.x, lane = t & 63, w = t >> 6;
  if (t == 0) carry = 0;
  __syncthreads();
  for (int base = 0; base < nb; base += 256) {
    int i = base + t;
    int v = (i < nb) ? b[i] : 0;
    int x = v;
#pragma unroll
    for (int o = 1; o < 64; o <<= 1) { int u = __shfl_up(x, o, 64); if (lane >= o) x += u; }
    if (lane == 63) ws[w] = x;
    __syncthreads();
    if (t == 0) { int s = 0; for (int k = 0; k < 4; k++) { int tmp = ws[k]; ws[k] = s; s += tmp; } }
    __syncthreads();
    int excl = x - v + ws[w] + carry;
    if (i < nb) b[i] = excl;
    __syncthreads();
    if (t == 255) carry = excl + v;
    __syncthreads();
  }
}

__global__ __launch_bounds__(256) void k_scan3(
    int* __restrict__ off, const int* __restrict__ bsum, int N, int E)
{
  int i = blockIdx.x * 256 + threadIdx.x;
  if (i < N) off[i] += bsum[blockIdx.x];
  if (i == 0) off[N] = E;
}

// ---------------- scatter edges into CSR slots ----------------
__global__ __launch_bounds__(256) void k_scatter(
    const int* __restrict__ src, const int* __restrict__ dst,
    const int* __restrict__ rank, const int* __restrict__ off,
    int* __restrict__ csr, int E)
{
  int e = blockIdx.x * 256 + threadIdx.x;
  if (e >= E) return;
  csr[off[dst[e]] + rank[e]] = src[e];
}

// ---------------- gather pass, layer 1 (H=2,D=4): atomic-free softmax-aggregate ----------------
__global__ __launch_bounds__(256) void k_gather1(
    const int* __restrict__ csr, const int* __restrict__ off,
    const float* __restrict__ as_, const float* __restrict__ ad_,
    const float* __restrict__ xps, float* __restrict__ out, int N)
{
  int d = blockIdx.x * 256 + threadIdx.x;
  if (d >= N) return;
  int i0 = off[d], i1 = off[d + 1];
  float2 adv = ((const float2*)ad_)[d];
  float s0 = 0.f, s1 = 0.f;
  float acc[8] = {0.f, 0.f, 0.f, 0.f, 0.f, 0.f, 0.f, 0.f};
  for (int i = i0; i < i1; i++) {
    int s = csr[i];
    float2 av = ((const float2*)as_)[s];
    float a0 = av.x + adv.x; a0 = a0 > 0.f ? a0 : 0.2f * a0;
    float a1 = av.y + adv.y; a1 = a1 > 0.f ? a1 : 0.2f * a1;
    float e0 = __expf(a0), e1 = __expf(a1);
    s0 += e0; s1 += e1;
    float4 x0 = ((const float4*)xps)[s * 2];
    float4 x1 = ((const float4*)xps)[s * 2 + 1];
    acc[0] += e0 * x0.x; acc[1] += e0 * x0.y; acc[2] += e0 * x0.z; acc[3] += e0 * x0.w;
    acc[4] += e1 * x1.x; acc[5] += e1 * x1.y; acc[6] += e1 * x1.z; acc[7] += e1 * x1.w;
  }
  float r0 = 1.f / (s0 + 1e-16f), r1 = 1.f / (s1 + 1e-16f);
  float4 o0, o1;
  o0.x = fmaxf(acc[0] * r0, 0.f); o0.y = fmaxf(acc[1] * r0, 0.f);
  o0.z = fmaxf(acc[2] * r0, 0.f); o0.w = fmaxf(acc[3] * r0, 0.f);
  o1.x = fmaxf(acc[4] * r1, 0.f); o1.y = fmaxf(acc[5] * r1, 0.f);
  o1.z = fmaxf(acc[6] * r1, 0.f); o1.w = fmaxf(acc[7] * r1, 0.f);
  ((float4*)out)[d * 2] = o0;
  ((float4*)out)[d * 2 + 1] = o1;
}

// ---------------- gather pass, layer 2 (H=1, F=7 padded 8) ----------------
__global__ __launch_bounds__(256) void k_gather2(
    const int* __restrict__ csr, const int* __restrict__ off,
    const float* __restrict__ as_, const float* __restrict__ ad_,
    const float* __restrict__ xps, float* __restrict__ out, int N)
{
  int d = blockIdx.x * 256 + threadIdx.x;
  if (d >= N) return;
  int i0 = off[d], i1 = off[d + 1];
  float adv = ad_[d];
  float ssum = 0.f;
  float acc[7] = {0.f, 0.f, 0.f, 0.f, 0.f, 0.f, 0.f};
  for (int i = i0; i < i1; i++) {
    int s = csr[i];
    float a = as_[s] + adv; a = a > 0.f ? a : 0.2f * a;
    float ex = __expf(a);
    ssum += ex;
    float4 x0 = ((const float4*)xps)[s * 2];
    float4 x1 = ((const float4*)xps)[s * 2 + 1];
    acc[0] += ex * x0.x; acc[1] += ex * x0.y; acc[2] += ex * x0.z; acc[3] += ex * x0.w;
    acc[4] += ex * x1.x; acc[5] += ex * x1.y; acc[6] += ex * x1.z;
  }
  float r = 1.f / (ssum + 1e-16f);
  float4 o0, o1;
  o0.x = fmaxf(acc[0] * r, 0.f); o0.y = fmaxf(acc[1] * r, 0.f);
  o0.z = fmaxf(acc[2] * r, 0.f); o0.w = fmaxf(acc[3] * r, 0.f);
  o1.x = fmaxf(acc[4] * r, 0.f); o1.y = fmaxf(acc[5] * r, 0.f);
  o1.z = fmaxf(acc[6] * r, 0.f); o1.w = 0.f;
  ((float4*)out)[d * 2] = o0;
  ((float4*)out)[d * 2 + 1] = o1;
}

// ---------------- semantic-attention reduction: red[f] += sum_n tanh(h[n]@kw+kb)[f] ----------------
__global__ __launch_bounds__(256) void k_red(
    const float* __restrict__ h, int N, int F,
    const float* __restrict__ kw, const float* __restrict__ kb,
    float* __restrict__ red)
{
  __shared__ float kws[64], kbs[8];
  __shared__ float sm[256 * 8];
  int t = threadIdx.x;
  if (t < F * F) kws[t] = kw[t];
  if (t < F) kbs[t] = kb[t];
  __syncthreads();
  float acc[8] = {0, 0, 0, 0, 0, 0, 0, 0};
  for (int n = blockIdx.x * 256 + t; n < N; n += gridDim.x * 256) {
    const float* row = h + (size_t)n * 8;
    float xv[8];
    for (int k = 0; k < F; k++) xv[k] = row[k];
    for (int f = 0; f < F; f++) {
      float s = kbs[f];
      for (int k = 0; k < F; k++) s += xv[k] * kws[k * F + f];
      acc[f] += tanhf(s);
    }
  }
  for (int f = 0; f < 8; f++) sm[t * 8 + f] = (f < F) ? acc[f] : 0.f;
  __syncthreads();
  for (int s2 = 128; s2 > 0; s2 >>= 1) {
    if (t < s2)
      for (int f = 0; f < 8; f++) sm[t * 8 + f] += sm[(t + s2) * 8 + f];
    __syncthreads();
  }
  if (t < F) atomicAdd(&red[t], sm[t]);
}

// ---------------- semantic attention weights (tiny) ----------------
__global__ void k_attn(const float* __restrict__ red, const float* __restrict__ q,
                       int T, int F, float invN, float* __restrict__ attn)
{
  if (threadIdx.x != 0 || blockIdx.x != 0) return;
  float v[4]; float m = -1e30f;
  for (int t2 = 0; t2 < T; t2++) {
    float s = 0.f;
    for (int f = 0; f < F; f++) s += q[f] * red[t2 * F + f];
    s *= invN;
    v[t2] = s; m = fmaxf(m, s);
  }
  float sum = 0.f;
  for (int t2 = 0; t2 < T; t2++) { v[t2] = __expf(v[t2] - m); sum += v[t2]; }
  for (int t2 = 0; t2 < T; t2++) attn[t2] = v[t2] / sum;
}

// ---------------- weighted combine (+relu) ----------------
__global__ __launch_bounds__(256) void k_comb(
    const float* __restrict__ h0, const float* __restrict__ h1,
    const float* __restrict__ attn, float* __restrict__ out, int NF)
{
  int i = blockIdx.x * blockDim.x + threadIdx.x;
  if (i >= NF) return;
  float v = attn[0] * h0[i] + attn[1] * h1[i];
  out[i] = v > 0.f ? v : 0.f;
}

// ---------------- layer-2 projection (8->7, padded stride 8) + fused alpha2 ----------------
__global__ __launch_bounds__(256) void k_proj2(
    const float* __restrict__ xin, int N,
    const float* __restrict__ w, const float* __restrict__ b,
    float* __restrict__ xp2,
    const float* __restrict__ pa0, float* __restrict__ oa0,
    const float* __restrict__ pa1, float* __restrict__ oa1,
    const float* __restrict__ pa2, float* __restrict__ oa2)
{
  int n = blockIdx.x * blockDim.x + threadIdx.x;
  if (n >= N) return;
  float4 a4 = ((const float4*)xin)[n * 2];
  float4 b4 = ((const float4*)xin)[n * 2 + 1];
  float xv[8] = {a4.x, a4.y, a4.z, a4.w, b4.x, b4.y, b4.z, b4.w};
  float y[7];
  for (int j = 0; j < 7; j++) y[j] = b[j];
  for (int k = 0; k < 8; k++) {
    float xk = xv[k];
    for (int j = 0; j < 7; j++) y[j] += xk * w[k * 7 + j];
  }
  ((float4*)xp2)[n * 2] = make_float4(y[0], y[1], y[2], y[3]);
  ((float4*)xp2)[n * 2 + 1] = make_float4(y[4], y[5], y[6], 0.f);
#define DOA2(p, o)                                      \
  if (p) {                                              \
    float s = 0.f;                                      \
    for (int j = 0; j < 7; j++) s += y[j] * p[j];       \
    o[n] = s;                                           \
  }
  DOA2(pa0, oa0) DOA2(pa1, oa1) DOA2(pa2, oa2)
#undef DOA2
}

// ---------------- final combine + log_softmax ----------------
__global__ __launch_bounds__(256) void k_final(
    const float* __restrict__ h0, const float* __restrict__ h1,
    const float* __restrict__ attn, float* __restrict__ out, int N)
{
  int n = blockIdx.x * blockDim.x + threadIdx.x;
  if (n >= N) return;
  float a0 = attn[0], a1 = attn[1];
  const float* r0 = h0 + (size_t)n * 8;
  const float* r1 = h1 + (size_t)n * 8;
  float v[7]; float m = -1e30f;
  for (int c = 0; c < 7; c++) { float t = a0 * r0[c] + a1 * r1[c]; v[c] = t; m = fmaxf(m, t); }
  float sum = 0.f;
  for (int c = 0; c < 7; c++) sum += __expf(v[c] - m);
  float lse = m + logf(sum);
  for (int c = 0; c < 7; c++) out[(size_t)n * 7 + c] = v[c] - lse;
}

extern "C" void kernel_launch(void* const* d_in, const int* in_sizes, int n_in,
                              void* d_out, int out_size, void* d_ws, size_t ws_size,
                              hipStream_t stream)
{
  const float* x_p  = (const float*)d_in[0];
  const float* x_a  = (const float*)d_in[1];
  const int*   eipp = (const int*)d_in[2];
  const int*   eipa = (const int*)d_in[3];
  const int*   eiap = (const int*)d_in[4];
  const float* w1p  = (const float*)d_in[5];
  const float* b1p  = (const float*)d_in[6];
  const float* w1a  = (const float*)d_in[7];
  const float* b1a  = (const float*)d_in[8];
  const float* as1pp = (const float*)d_in[9];
  const float* ad1pp = (const float*)d_in[10];
  const float* as1pa = (const float*)d_in[11];
  const float* ad1pa = (const float*)d_in[12];
  const float* as1ap = (const float*)d_in[13];
  const float* ad1ap = (const float*)d_in[14];
  const float* kw1 = (const float*)d_in[15];
  const float* kb1 = (const float*)d_in[16];
  const float* q1  = (const float*)d_in[17];
  const float* w2p = (const float*)d_in[18];
  const float* b2p = (const float*)d_in[19];
  const float* w2a = (const float*)d_in[20];
  const float* b2a = (const float*)d_in[21];
  const float* as2pp = (const float*)d_in[22];
  const float* ad2pp = (const float*)d_in[23];
  // d_in[24]=as2pa, d_in[25]=ad2pa unused: pa edges only feed author nodes,
  // and author layer-2 output is dead (final output is papers only).
  const float* as2ap = (const float*)d_in[26];
  const float* ad2ap = (const float*)d_in[27];
  const float* kw2 = (const float*)d_in[28];
  const float* kb2 = (const float*)d_in[29];
  const float* q2  = (const float*)d_in[30];

  const int NP = in_sizes[0] / DIN;
  const int NA = in_sizes[1] / DIN;
  const int E  = in_sizes[2] / 2;
  (void)n_in; (void)out_size; (void)ws_size;

  float* w = (float*)d_ws;
  size_t off_ = 0;
  auto A = [&](size_t n) { float* p = w + off_; off_ += (n + 3) & ~(size_t)3; return p; };
  // node buffers
  float* XP_P1 = A((size_t)NP * 8);
  float* XP_A1 = A((size_t)NA * 8);
  float* AS_PP = A((size_t)NP * 2);
  float* AD_PP = A((size_t)NP * 2);
  float* AS_PA = A((size_t)NP * 2);
  float* AD_PA = A((size_t)NA * 2);
  float* AS_AP = A((size_t)NA * 2);
  float* AD_AP = A((size_t)NP * 2);
  float* XP2_P = A((size_t)NP * 8);
  float* XP2_A = A((size_t)NA * 8);
  float* A2SPP = A((size_t)NP);
  float* A2DPP = A((size_t)NP);
  float* A2DAP = A((size_t)NP);
  float* A2SAP = A((size_t)NA);
  float* XPAP2 = A((size_t)NP * 8);
  float* O_PP  = A((size_t)NP * 8);
  float* O_PA  = A((size_t)NA * 8);
  float* O_AP  = A((size_t)NP * 8);
  float* O2PP  = A((size_t)NP * 8);
  float* O2AP  = A((size_t)NP * 8);
  float* ATT1  = A(2);
  float* ATT2  = A(2);
  // CSR structures (graph is identical for both layers -> build once, use 5x)
  int* CSR_PP = (int*)A((size_t)E);
  int* CSR_PA = (int*)A((size_t)E);
  int* CSR_AP = (int*)A((size_t)E);
  int* RANK   = (int*)A((size_t)E);          // shared across the 3 sequential builds
  int* OFF_PP = (int*)A((size_t)NP + 1);
  int* OFF_PA = (int*)A((size_t)NA + 1);
  int* OFF_AP = (int*)A((size_t)NP + 1);
  int* BSUM   = (int*)A(512);
  // ---- zero-initialized region: degree histograms + semantic-attn accumulators ----
  float* ACC0 = w + off_;
  int* DEG_PP = (int*)A((size_t)NP);
  int* DEG_PA = (int*)A((size_t)NA);
  int* DEG_AP = (int*)A((size_t)NP);
  float* RED1 = A(16);
  float* RED2 = A(14);
  size_t accBytes = (size_t)((w + off_) - ACC0) * sizeof(float);

  hipMemsetAsync(ACC0, 0, accBytes, stream);

  dim3 B(256);
  int gE = (E + 255) / 256;
  int nbP = (NP + 255) / 256, nbA = (NA + 255) / 256;

  // layer 1 projections + per-node alphas (independent of CSR builds)
  k_proj1<<<(NP + 31) / 32, B, 0, stream>>>(x_p, w1p, b1p, XP_P1, NP);
  k_proj1<<<(NA + 31) / 32, B, 0, stream>>>(x_a, w1a, b1a, XP_A1, NA);
  k_alpha1<<<nbP, B, 0, stream>>>(XP_P1, NP,
      as1pp, AS_PP, ad1pp, AD_PP, as1pa, AS_PA, ad1ap, AD_AP);
  k_alpha1<<<nbA, B, 0, stream>>>(XP_A1, NA,
      ad1pa, AD_PA, as1ap, AS_AP, nullptr, nullptr, nullptr, nullptr);

  // ---- CSR build + layer-1 gather, edge type pp (dst = paper) ----
  k_hist<<<gE, B, 0, stream>>>(eipp + E, E, DEG_PP, RANK);
  k_scan1<<<nbP, B, 0, stream>>>(DEG_PP, NP, OFF_PP, BSUM);
  k_scan2<<<1, B, 0, stream>>>(BSUM, nbP);
  k_scan3<<<nbP, B, 0, stream>>>(OFF_PP, BSUM, NP, E);
  k_scatter<<<gE, B, 0, stream>>>(eipp, eipp + E, RANK, OFF_PP, CSR_PP, E);
  k_gather1<<<nbP, B, 0, stream>>>(CSR_PP, OFF_PP, AS_PP, AD_PP, XP_P1, O_PP, NP);

  // ---- edge type pa (dst = author) ----
  k_hist<<<gE, B, 0, stream>>>(eipa + E, E, DEG_PA, RANK);
  k_scan1<<<nbA, B, 0, stream>>>(DEG_PA, NA, OFF_PA, BSUM);
  k_scan2<<<1, B, 0, stream>>>(BSUM, nbA);
  k_scan3<<<nbA, B, 0, stream>>>(OFF_PA, BSUM, NA, E);
  k_scatter<<<gE, B, 0, stream>>>(eipa, eipa + E, RANK, OFF_PA, CSR_PA, E);
  k_gather1<<<nbA, B, 0, stream>>>(CSR_PA, OFF_PA, AS_PA, AD_PA, XP_P1, O_PA, NA);

  // ---- edge type ap (dst = paper) ----
  k_hist<<<gE, B, 0, stream>>>(eiap + E, E, DEG_AP, RANK);
  k_scan1<<<nbP, B, 0, stream>>>(DEG_AP, NP, OFF_AP, BSUM);
  k_scan2<<<1, B, 0, stream>>>(BSUM, nbP);
  k_scan3<<<nbP, B, 0, stream>>>(OFF_AP, BSUM, NP, E);
  k_scatter<<<gE, B, 0, stream>>>(eiap, eiap + E, RANK, OFF_AP, CSR_AP, E);
  k_gather1<<<nbP, B, 0, stream>>>(CSR_AP, OFF_AP, AS_AP, AD_AP, XP_A1, O_AP, NP);

  // layer 1 semantic attention (paper: T=2; author: T=1 -> weight 1, O_PA passes through)
  k_red<<<256, B, 0, stream>>>(O_PP, NP, 8, kw1, kb1, RED1);
  k_red<<<256, B, 0, stream>>>(O_AP, NP, 8, kw1, kb1, RED1 + 8);
  k_attn<<<1, 1, 0, stream>>>(RED1, q1, 2, 8, 1.0f / NP, ATT1);
  k_comb<<<(NP * 8 + 255) / 256, B, 0, stream>>>(O_PP, O_AP, ATT1, XPAP2, NP * 8);

  // layer 2 projections + fused alphas
  k_proj2<<<nbP, B, 0, stream>>>(XPAP2, NP, w2p, b2p, XP2_P,
      as2pp, A2SPP, ad2pp, A2DPP, ad2ap, A2DAP);
  k_proj2<<<nbA, B, 0, stream>>>(O_PA, NA, w2a, b2a, XP2_A,
      as2ap, A2SAP, nullptr, nullptr, nullptr, nullptr);

  // layer 2 gathers (reuse CSR; pp and ap only — author layer-2 output is dead)
  k_gather2<<<nbP, B, 0, stream>>>(CSR_PP, OFF_PP, A2SPP, A2DPP, XP2_P, O2PP, NP);
  k_gather2<<<nbP, B, 0, stream>>>(CSR_AP, OFF_AP, A2SAP, A2DAP, XP2_A, O2AP, NP);

  // layer 2 semantic attention + final log_softmax
  k_red<<<256, B, 0, stream>>>(O2PP, NP, 7, kw2, kb2, RED2);
  k_red<<<256, B, 0, stream>>>(O2AP, NP, 7, kw2, kb2, RED2 + 7);
  k_attn<<<1, 1, 0, stream>>>(RED2, q2, 2, 7, 1.0f / NP, ATT2);
  k_final<<<nbP, B, 0, stream>>>(O2PP, O2AP, ATT2, (float*)d_out, NP);
}

// Round 4
// 937.067 us; speedup vs baseline: 7.9663x; 1.1590x over previous
//
#include <hip/hip_runtime.h>

constexpr int DIN = 128, HIDF = 8;
constexpr int BPG = 8192, LOGB = 13;   // LDS-histogram bins per group; group = d >> 13
constexpr int LOGC = 17;               // edges per chunk = 131072

// ---------------- layer-1 projection: xp[N,8] = x[N,128] @ w[128,8] + b ----------------
__global__ __launch_bounds__(256) void k_proj1(
    const float* __restrict__ x, const float* __restrict__ w,
    const float* __restrict__ b, float* __restrict__ xp, int N)
{
  __shared__ float ws_[DIN * HIDF];
  __shared__ float xs[32 * 132];
  int t = threadIdx.x;
  ((float4*)ws_)[t] = ((const float4*)w)[t];
  int base = blockIdx.x * 32;
#pragma unroll
  for (int i = 0; i < 4; i++) {
    int f4 = t + i * 256;
    int nl = f4 >> 5;
    if (base + nl < N) {
      float4 v = ((const float4*)(x + (size_t)base * DIN))[f4];
      int col = (f4 & 31) << 2;
      *((float4*)&xs[nl * 132 + col]) = v;
    }
  }
  __syncthreads();
  int nl = t >> 3, j = t & 7;
  int n0 = base + nl;
  if (n0 >= N) return;
  float acc = b[j];
  const float* xr = &xs[nl * 132];
#pragma unroll 8
  for (int k = 0; k < DIN; k++) acc = fmaf(xr[k], ws_[k * HIDF + j], acc);
  xp[(size_t)n0 * HIDF + j] = acc;
}

// ---------------- per-node attention coefficients, layer 1 (H=2, D=4) ----------------
__global__ __launch_bounds__(256) void k_alpha1(
    const float* __restrict__ xp, int N,
    const float* __restrict__ p0, float* __restrict__ o0,
    const float* __restrict__ p1, float* __restrict__ o1,
    const float* __restrict__ p2, float* __restrict__ o2,
    const float* __restrict__ p3, float* __restrict__ o3)
{
  int n = blockIdx.x * blockDim.x + threadIdx.x;
  if (n >= N) return;
  float4 a4 = ((const float4*)xp)[n * 2];
  float4 b4 = ((const float4*)xp)[n * 2 + 1];
  float xv[8] = {a4.x, a4.y, a4.z, a4.w, b4.x, b4.y, b4.z, b4.w};
#define DOA(p, o)                                                     \
  if (p) {                                                            \
    float s0 = 0.f, s1 = 0.f;                                         \
    for (int d = 0; d < 4; d++) { s0 += xv[d] * p[d]; s1 += xv[4 + d] * p[4 + d]; } \
    ((float2*)o)[n] = make_float2(s0, s1);                            \
  }
  DOA(p0, o0) DOA(p1, o1) DOA(p2, o2) DOA(p3, o3)
#undef DOA
}

// ---------------- CSR build phase A: LDS-privatized count + local rank (NO global atomics) --------
// grid: (nChunks, G). Block (c,g) counts dst in [g*BPG,(g+1)*BPG) over edge chunk c.
__global__ __launch_bounds__(512) void k_count(
    const int* __restrict__ dst, int E, int* __restrict__ P,
    int* __restrict__ lrank, int nc)
{
  __shared__ int lh[BPG];
  int c = blockIdx.x, g = blockIdx.y, t = threadIdx.x;
  for (int i = t; i < BPG; i += 512) lh[i] = 0;
  __syncthreads();
  int e0 = c << LOGC, e1 = min(E, e0 + (1 << LOGC));
  for (int e = e0 + t; e < e1; e += 512) {
    int d = dst[e];
    if ((d >> LOGB) == g) lrank[e] = atomicAdd(&lh[d & (BPG - 1)], 1);
  }
  __syncthreads();
  int* Pb = P + ((size_t)g * nc + c) * BPG;
  for (int i = t; i < BPG; i += 512) Pb[i] = lh[i];
}

// ---------------- phase B1: per-bin prefix over chunks (in place) + total degree ----------------
__global__ __launch_bounds__(256) void k_chunkscan(
    int* __restrict__ P, int* __restrict__ deg, int nc, int G, int N)
{
  int bin = blockIdx.x * 256 + threadIdx.x;       // bin id == (g<<LOGB)|b
  if (bin >= G * BPG) return;
  int g = bin >> LOGB, b = bin & (BPG - 1);
  int* base = P + (size_t)g * nc * BPG + b;
  int run = 0;
  for (int c = 0; c < nc; c++) {
    int v = base[(size_t)c * BPG];
    base[(size_t)c * BPG] = run;
    run += v;
  }
  if (bin < N) deg[bin] = run;
}

// ---------------- exclusive scan, 3-phase (N ~ 100k) ----------------
__global__ __launch_bounds__(256) void k_scan1(
    const int* __restrict__ deg, int N, int* __restrict__ off, int* __restrict__ bsum)
{
  int t = threadIdx.x;
  int i = blockIdx.x * 256 + t;
  int v = (i < N) ? deg[i] : 0;
  int lane = t & 63, w = t >> 6;
  int x = v;
#pragma unroll
  for (int o = 1; o < 64; o <<= 1) { int u = __shfl_up(x, o, 64); if (lane >= o) x += u; }
  __shared__ int ws[4];
  if (lane == 63) ws[w] = x;
  __syncthreads();
  if (t == 0) { int s = 0; for (int k = 0; k < 4; k++) { int tmp = ws[k]; ws[k] = s; s += tmp; } }
  __syncthreads();
  int excl = x - v + ws[w];
  if (i < N) off[i] = excl;
  if (t == 255) bsum[blockIdx.x] = excl + v;
}

__global__ __launch_bounds__(256) void k_scan2(int* __restrict__ b, int nb)
{
  __shared__ int ws[4];
  __shared__ int carry;
  int t = threadIdx.x, lane = t & 63, w = t >> 6;
  if (t == 0) carry = 0;
  __syncthreads();
  for (int base = 0; base < nb; base += 256) {
    int i = base + t;
    int v = (i < nb) ? b[i] : 0;
    int x = v;
#pragma unroll
    for (int o = 1; o < 64; o <<= 1) { int u = __shfl_up(x, o, 64); if (lane >= o) x += u; }
    if (lane == 63) ws[w] = x;
    __syncthreads();
    if (t == 0) { int s = 0; for (int k = 0; k < 4; k++) { int tmp = ws[k]; ws[k] = s; s += tmp; } }
    __syncthreads();
    int excl = x - v + ws[w] + carry;
    if (i < nb) b[i] = excl;
    __syncthreads();
    if (t == 255) carry = excl + v;
    __syncthreads();
  }
}

__global__ __launch_bounds__(256) void k_scan3(
    int* __restrict__ off, const int* __restrict__ bsum, int N, int E)
{
  int i = blockIdx.x * 256 + threadIdx.x;
  if (i < N) off[i] += bsum[blockIdx.x];
  if (i == 0) off[N] = E;
}

// ---------------- phase C: edge-parallel placement (no atomics) ----------------
__global__ __launch_bounds__(256) void k_place(
    const int* __restrict__ src, const int* __restrict__ dst,
    const int* __restrict__ lrank, const int* __restrict__ off,
    const int* __restrict__ P, int* __restrict__ csr, int E, int nc)
{
  int e = blockIdx.x * 256 + threadIdx.x;
  if (e >= E) return;
  int d = dst[e], s = src[e];
  int g = d >> LOGB, b = d & (BPG - 1), c = e >> LOGC;
  int pos = off[d] + P[((size_t)g * nc + c) * BPG + b] + lrank[e];
  csr[pos] = s;
}

// ---------------- gather, layer 1 (H=2,D=4): 8 lanes per dst ----------------
__global__ __launch_bounds__(256) void k_gather1(
    const int* __restrict__ csr, const int* __restrict__ off,
    const float* __restrict__ as_, const float* __restrict__ ad_,
    const float* __restrict__ xps, float* __restrict__ out, int N)
{
  int t = blockIdx.x * 256 + threadIdx.x;
  int d = t >> 3, l = t & 7;
  if (d >= N) return;
  int i0 = off[d], i1 = off[d + 1];
  float2 adv = ((const float2*)ad_)[d];
  float s0 = 0.f, s1 = 0.f;
  float acc[8] = {0.f, 0.f, 0.f, 0.f, 0.f, 0.f, 0.f, 0.f};
  for (int i = i0 + l; i < i1; i += 8) {
    int s = csr[i];
    float2 av = ((const float2*)as_)[s];
    float a0 = av.x + adv.x; a0 = a0 > 0.f ? a0 : 0.2f * a0;
    float a1 = av.y + adv.y; a1 = a1 > 0.f ? a1 : 0.2f * a1;
    float e0 = __expf(a0), e1 = __expf(a1);
    s0 += e0; s1 += e1;
    float4 x0 = ((const float4*)xps)[s * 2];
    float4 x1 = ((const float4*)xps)[s * 2 + 1];
    acc[0] += e0 * x0.x; acc[1] += e0 * x0.y; acc[2] += e0 * x0.z; acc[3] += e0 * x0.w;
    acc[4] += e1 * x1.x; acc[5] += e1 * x1.y; acc[6] += e1 * x1.z; acc[7] += e1 * x1.w;
  }
#pragma unroll
  for (int m = 1; m < 8; m <<= 1) {
    s0 += __shfl_xor(s0, m, 8);
    s1 += __shfl_xor(s1, m, 8);
#pragma unroll
    for (int k = 0; k < 8; k++) acc[k] += __shfl_xor(acc[k], m, 8);
  }
  if (l) return;
  float r0 = 1.f / (s0 + 1e-16f), r1 = 1.f / (s1 + 1e-16f);
  float4 o0, o1;
  o0.x = fmaxf(acc[0] * r0, 0.f); o0.y = fmaxf(acc[1] * r0, 0.f);
  o0.z = fmaxf(acc[2] * r0, 0.f); o0.w = fmaxf(acc[3] * r0, 0.f);
  o1.x = fmaxf(acc[4] * r1, 0.f); o1.y = fmaxf(acc[5] * r1, 0.f);
  o1.z = fmaxf(acc[6] * r1, 0.f); o1.w = fmaxf(acc[7] * r1, 0.f);
  ((float4*)out)[(size_t)d * 2] = o0;
  ((float4*)out)[(size_t)d * 2 + 1] = o1;
}

// ---------------- gather, layer 2 (H=1, F=7 padded 8): 8 lanes per dst ----------------
__global__ __launch_bounds__(256) void k_gather2(
    const int* __restrict__ csr, const int* __restrict__ off,
    const float* __restrict__ as_, const float* __restrict__ ad_,
    const float* __restrict__ xps, float* __restrict__ out, int N)
{
  int t = blockIdx.x * 256 + threadIdx.x;
  int d = t >> 3, l = t & 7;
  if (d >= N) return;
  int i0 = off[d], i1 = off[d + 1];
  float adv = ad_[d];
  float ssum = 0.f;
  float acc[7] = {0.f, 0.f, 0.f, 0.f, 0.f, 0.f, 0.f};
  for (int i = i0 + l; i < i1; i += 8) {
    int s = csr[i];
    float a = as_[s] + adv; a = a > 0.f ? a : 0.2f * a;
    float ex = __expf(a);
    ssum += ex;
    float4 x0 = ((const float4*)xps)[s * 2];
    float4 x1 = ((const float4*)xps)[s * 2 + 1];
    acc[0] += ex * x0.x; acc[1] += ex * x0.y; acc[2] += ex * x0.z; acc[3] += ex * x0.w;
    acc[4] += ex * x1.x; acc[5] += ex * x1.y; acc[6] += ex * x1.z;
  }
#pragma unroll
  for (int m = 1; m < 8; m <<= 1) {
    ssum += __shfl_xor(ssum, m, 8);
#pragma unroll
    for (int k = 0; k < 7; k++) acc[k] += __shfl_xor(acc[k], m, 8);
  }
  if (l) return;
  float r = 1.f / (ssum + 1e-16f);
  float4 o0, o1;
  o0.x = fmaxf(acc[0] * r, 0.f); o0.y = fmaxf(acc[1] * r, 0.f);
  o0.z = fmaxf(acc[2] * r, 0.f); o0.w = fmaxf(acc[3] * r, 0.f);
  o1.x = fmaxf(acc[4] * r, 0.f); o1.y = fmaxf(acc[5] * r, 0.f);
  o1.z = fmaxf(acc[6] * r, 0.f); o1.w = 0.f;
  ((float4*)out)[(size_t)d * 2] = o0;
  ((float4*)out)[(size_t)d * 2 + 1] = o1;
}

// ---------------- semantic-attention reduction ----------------
__global__ __launch_bounds__(256) void k_red(
    const float* __restrict__ h, int N, int F,
    const float* __restrict__ kw, const float* __restrict__ kb,
    float* __restrict__ red)
{
  __shared__ float kws[64], kbs[8];
  __shared__ float sm[256 * 8];
  int t = threadIdx.x;
  if (t < F * F) kws[t] = kw[t];
  if (t < F) kbs[t] = kb[t];
  __syncthreads();
  float acc[8] = {0, 0, 0, 0, 0, 0, 0, 0};
  for (int n = blockIdx.x * 256 + t; n < N; n += gridDim.x * 256) {
    const float* row = h + (size_t)n * 8;
    float xv[8];
    for (int k = 0; k < F; k++) xv[k] = row[k];
    for (int f = 0; f < F; f++) {
      float s = kbs[f];
      for (int k = 0; k < F; k++) s += xv[k] * kws[k * F + f];
      acc[f] += tanhf(s);
    }
  }
  for (int f = 0; f < 8; f++) sm[t * 8 + f] = (f < F) ? acc[f] : 0.f;
  __syncthreads();
  for (int s2 = 128; s2 > 0; s2 >>= 1) {
    if (t < s2)
      for (int f = 0; f < 8; f++) sm[t * 8 + f] += sm[(t + s2) * 8 + f];
    __syncthreads();
  }
  if (t < F) atomicAdd(&red[t], sm[t]);
}

// ---------------- semantic attention weights (tiny) ----------------
__global__ void k_attn(const float* __restrict__ red, const float* __restrict__ q,
                       int T, int F, float invN, float* __restrict__ attn)
{
  if (threadIdx.x != 0 || blockIdx.x != 0) return;
  float v[4]; float m = -1e30f;
  for (int t2 = 0; t2 < T; t2++) {
    float s = 0.f;
    for (int f = 0; f < F; f++) s += q[f] * red[t2 * F + f];
    s *= invN;
    v[t2] = s; m = fmaxf(m, s);
  }
  float sum = 0.f;
  for (int t2 = 0; t2 < T; t2++) { v[t2] = __expf(v[t2] - m); sum += v[t2]; }
  for (int t2 = 0; t2 < T; t2++) attn[t2] = v[t2] / sum;
}

// ---------------- weighted combine (+relu) ----------------
__global__ __launch_bounds__(256) void k_comb(
    const float* __restrict__ h0, const float* __restrict__ h1,
    const float* __restrict__ attn, float* __restrict__ out, int NF)
{
  int i = blockIdx.x * blockDim.x + threadIdx.x;
  if (i >= NF) return;
  float v = attn[0] * h0[i] + attn[1] * h1[i];
  out[i] = v > 0.f ? v : 0.f;
}

// ---------------- layer-2 projection (8->7, padded stride 8) + fused alpha2 ----------------
__global__ __launch_bounds__(256) void k_proj2(
    const float* __restrict__ xin, int N,
    const float* __restrict__ w, const float* __restrict__ b,
    float* __restrict__ xp2,
    const float* __restrict__ pa0, float* __restrict__ oa0,
    const float* __restrict__ pa1, float* __restrict__ oa1,
    const float* __restrict__ pa2, float* __restrict__ oa2)
{
  int n = blockIdx.x * blockDim.x + threadIdx.x;
  if (n >= N) return;
  float4 a4 = ((const float4*)xin)[n * 2];
  float4 b4 = ((const float4*)xin)[n * 2 + 1];
  float xv[8] = {a4.x, a4.y, a4.z, a4.w, b4.x, b4.y, b4.z, b4.w};
  float y[7];
  for (int j = 0; j < 7; j++) y[j] = b[j];
  for (int k = 0; k < 8; k++) {
    float xk = xv[k];
    for (int j = 0; j < 7; j++) y[j] += xk * w[k * 7 + j];
  }
  ((float4*)xp2)[(size_t)n * 2] = make_float4(y[0], y[1], y[2], y[3]);
  ((float4*)xp2)[(size_t)n * 2 + 1] = make_float4(y[4], y[5], y[6], 0.f);
#define DOA2(p, o)                                      \
  if (p) {                                              \
    float s = 0.f;                                      \
    for (int j = 0; j < 7; j++) s += y[j] * p[j];       \
    o[n] = s;                                           \
  }
  DOA2(pa0, oa0) DOA2(pa1, oa1) DOA2(pa2, oa2)
#undef DOA2
}

// ---------------- final combine + log_softmax ----------------
__global__ __launch_bounds__(256) void k_final(
    const float* __restrict__ h0, const float* __restrict__ h1,
    const float* __restrict__ attn, float* __restrict__ out, int N)
{
  int n = blockIdx.x * blockDim.x + threadIdx.x;
  if (n >= N) return;
  float a0 = attn[0], a1 = attn[1];
  const float* r0 = h0 + (size_t)n * 8;
  const float* r1 = h1 + (size_t)n * 8;
  float v[7]; float m = -1e30f;
  for (int c = 0; c < 7; c++) { float t = a0 * r0[c] + a1 * r1[c]; v[c] = t; m = fmaxf(m, t); }
  float sum = 0.f;
  for (int c = 0; c < 7; c++) sum += __expf(v[c] - m);
  float lse = m + logf(sum);
  for (int c = 0; c < 7; c++) out[(size_t)n * 7 + c] = v[c] - lse;
}

extern "C" void kernel_launch(void* const* d_in, const int* in_sizes, int n_in,
                              void* d_out, int out_size, void* d_ws, size_t ws_size,
                              hipStream_t stream)
{
  const float* x_p  = (const float*)d_in[0];
  const float* x_a  = (const float*)d_in[1];
  const int*   eipp = (const int*)d_in[2];
  const int*   eipa = (const int*)d_in[3];
  const int*   eiap = (const int*)d_in[4];
  const float* w1p  = (const float*)d_in[5];
  const float* b1p  = (const float*)d_in[6];
  const float* w1a  = (const float*)d_in[7];
  const float* b1a  = (const float*)d_in[8];
  const float* as1pp = (const float*)d_in[9];
  const float* ad1pp = (const float*)d_in[10];
  const float* as1pa = (const float*)d_in[11];
  const float* ad1pa = (const float*)d_in[12];
  const float* as1ap = (const float*)d_in[13];
  const float* ad1ap = (const float*)d_in[14];
  const float* kw1 = (const float*)d_in[15];
  const float* kb1 = (const float*)d_in[16];
  const float* q1  = (const float*)d_in[17];
  const float* w2p = (const float*)d_in[18];
  const float* b2p = (const float*)d_in[19];
  const float* w2a = (const float*)d_in[20];
  const float* b2a = (const float*)d_in[21];
  const float* as2pp = (const float*)d_in[22];
  const float* ad2pp = (const float*)d_in[23];
  // d_in[24]=as2pa, d_in[25]=ad2pa unused: pa edges only feed author nodes,
  // and author layer-2 output is dead (final output is papers only).
  const float* as2ap = (const float*)d_in[26];
  const float* ad2ap = (const float*)d_in[27];
  const float* kw2 = (const float*)d_in[28];
  const float* kb2 = (const float*)d_in[29];
  const float* q2  = (const float*)d_in[30];

  const int NP = in_sizes[0] / DIN;
  const int NA = in_sizes[1] / DIN;
  const int E  = in_sizes[2] / 2;
  (void)n_in; (void)out_size; (void)ws_size;

  const int nc = (E + (1 << LOGC) - 1) >> LOGC;
  const int GP = (NP + BPG - 1) / BPG;
  const int GA = (NA + BPG - 1) / BPG;
  const int Gmax = GP > GA ? GP : GA;

  float* w = (float*)d_ws;
  size_t off_ = 0;
  auto A = [&](size_t n) { float* p = w + off_; off_ += (n + 3) & ~(size_t)3; return p; };
  // node buffers (aliased across layers where lifetimes allow)
  float* XP_P1 = A((size_t)NP * 8);   // layer1 paper feats; reused as XP2_P after gather1s
  float* XP_A1 = A((size_t)NA * 8);   // layer1 author feats; reused as XP2_A
  float* AS_PP = A((size_t)NP * 2);   // reused as A2SPP
  float* AD_PP = A((size_t)NP * 2);   // reused as A2DPP
  float* AS_PA = A((size_t)NP * 2);   // reused as A2DAP
  float* AD_PA = A((size_t)NA * 2);   // reused as A2SAP
  float* AS_AP = A((size_t)NA * 2);
  float* AD_AP = A((size_t)NP * 2);
  float* XPAP2 = A((size_t)NP * 8);
  float* O_PP  = A((size_t)NP * 8);   // reused as O2PP after k_comb
  float* O_PA  = A((size_t)NA * 8);
  float* O_AP  = A((size_t)NP * 8);   // reused as O2AP after k_comb
  float* ATT1  = A(2);
  float* ATT2  = A(2);
  float* RED1  = A(16);
  float* RED2  = A(16);
  // CSR structures
  int* CSR_PP = (int*)A((size_t)E);
  int* CSR_PA = (int*)A((size_t)E);
  int* CSR_AP = (int*)A((size_t)E);
  int* OFF_PP = (int*)A((size_t)NP + 1);
  int* OFF_PA = (int*)A((size_t)NA + 1);
  int* OFF_AP = (int*)A((size_t)NP + 1);
  int* BSUM   = (int*)A(512);
  // transient per-build buffers (reused across the 3 sequential builds)
  int* LRANK  = (int*)A((size_t)E);
  int* DEG    = (int*)A((size_t)(NP > NA ? NP : NA));
  int* PBUF   = (int*)A((size_t)Gmax * nc * BPG);

  // aliases for layer 2
  float* XP2_P = XP_P1;
  float* XP2_A = XP_A1;
  float* A2SPP = AS_PP;
  float* A2DPP = AD_PP;
  float* A2DAP = AS_PA;
  float* A2SAP = AD_PA;
  float* O2PP  = O_PP;
  float* O2AP  = O_AP;

  hipMemsetAsync(RED1, 0, 32 * sizeof(float), stream);  // RED1+RED2 contiguous

  dim3 B(256);
  int nbP = (NP + 255) / 256, nbA = (NA + 255) / 256;
  int gE = (E + 255) / 256;
  int gG1P = (NP * 8 + 255) / 256, gG1A = (NA * 8 + 255) / 256;

  auto build = [&](const int* src, const int* dstp, int Nn, int Gn, int* csr, int* offv) {
    dim3 gA(nc, Gn);
    k_count<<<gA, dim3(512), 0, stream>>>(dstp, E, PBUF, LRANK, nc);
    int nbins = Gn * BPG;
    k_chunkscan<<<(nbins + 255) / 256, B, 0, stream>>>(PBUF, DEG, nc, Gn, Nn);
    int nb = (Nn + 255) / 256;
    k_scan1<<<nb, B, 0, stream>>>(DEG, Nn, offv, BSUM);
    k_scan2<<<1, B, 0, stream>>>(BSUM, nb);
    k_scan3<<<nb, B, 0, stream>>>(offv, BSUM, Nn, E);
    k_place<<<gE, B, 0, stream>>>(src, dstp, LRANK, offv, PBUF, csr, E, nc);
  };

  // layer 1 projections + per-node alphas
  k_proj1<<<(NP + 31) / 32, B, 0, stream>>>(x_p, w1p, b1p, XP_P1, NP);
  k_proj1<<<(NA + 31) / 32, B, 0, stream>>>(x_a, w1a, b1a, XP_A1, NA);
  k_alpha1<<<nbP, B, 0, stream>>>(XP_P1, NP,
      as1pp, AS_PP, ad1pp, AD_PP, as1pa, AS_PA, ad1ap, AD_AP);
  k_alpha1<<<nbA, B, 0, stream>>>(XP_A1, NA,
      ad1pa, AD_PA, as1ap, AS_AP, nullptr, nullptr, nullptr, nullptr);

  // builds + layer-1 gathers
  build(eipp, eipp + E, NP, GP, CSR_PP, OFF_PP);
  k_gather1<<<gG1P, B, 0, stream>>>(CSR_PP, OFF_PP, AS_PP, AD_PP, XP_P1, O_PP, NP);
  build(eipa, eipa + E, NA, GA, CSR_PA, OFF_PA);
  k_gather1<<<gG1A, B, 0, stream>>>(CSR_PA, OFF_PA, AS_PA, AD_PA, XP_P1, O_PA, NA);
  build(eiap, eiap + E, NP, GP, CSR_AP, OFF_AP);
  k_gather1<<<gG1P, B, 0, stream>>>(CSR_AP, OFF_AP, AS_AP, AD_AP, XP_A1, O_AP, NP);

  // layer 1 semantic attention (paper: T=2; author: T=1 -> O_PA passes through)
  k_red<<<256, B, 0, stream>>>(O_PP, NP, 8, kw1, kb1, RED1);
  k_red<<<256, B, 0, stream>>>(O_AP, NP, 8, kw1, kb1, RED1 + 8);
  k_attn<<<1, 1, 0, stream>>>(RED1, q1, 2, 8, 1.0f / NP, ATT1);
  k_comb<<<gG1P, B, 0, stream>>>(O_PP, O_AP, ATT1, XPAP2, NP * 8);

  // layer 2 projections + fused alphas (XP2_* alias XP_*1 — safe: layer-1 feats dead)
  k_proj2<<<nbP, B, 0, stream>>>(XPAP2, NP, w2p, b2p, XP2_P,
      as2pp, A2SPP, ad2pp, A2DPP, ad2ap, A2DAP);
  k_proj2<<<nbA, B, 0, stream>>>(O_PA, NA, w2a, b2a, XP2_A,
      as2ap, A2SAP, nullptr, nullptr, nullptr, nullptr);

  // layer 2 gathers (reuse CSR; pp and ap only — author layer-2 output is dead)
  k_gather2<<<gG1P, B, 0, stream>>>(CSR_PP, OFF_PP, A2SPP, A2DPP, XP2_P, O2PP, NP);
  k_gather2<<<gG1P, B, 0, stream>>>(CSR_AP, OFF_AP, A2SAP, A2DAP, XP2_A, O2AP, NP);

  // layer 2 semantic attention + final log_softmax
  k_red<<<256, B, 0, stream>>>(O2PP, NP, 7, kw2, kb2, RED2);
  k_red<<<256, B, 0, stream>>>(O2AP, NP, 7, kw2, kb2, RED2 + 7);
  k_attn<<<1, 1, 0, stream>>>(RED2, q2, 2, 7, 1.0f / NP, ATT2);
  k_final<<<nbP, B, 0, stream>>>(O2PP, O2AP, ATT2, (float*)d_out, NP);
}

// Round 5
// 617.825 us; speedup vs baseline: 12.0826x; 1.5167x over previous
//
#include <hip/hip_runtime.h>

constexpr int DIN = 128, HIDF = 8;
constexpr int LOGB = 14, BPG = 1 << LOGB;  // 16384 bins/group, 2 packed per LDS word
constexpr int W = BPG / 2;                  // 8192 words = 32KB LDS
constexpr int LOGC = 17;                    // 131072 edges per chunk

// ---------------- layer-1 projection: xp[N,8] = x[N,128] @ w[128,8] + b ----------------
__global__ __launch_bounds__(256) void k_proj1(
    const float* __restrict__ x, const float* __restrict__ w,
    const float* __restrict__ b, float* __restrict__ xp, int N)
{
  __shared__ float ws_[DIN * HIDF];
  __shared__ float xs[32 * 132];
  int t = threadIdx.x;
  ((float4*)ws_)[t] = ((const float4*)w)[t];
  int base = blockIdx.x * 32;
#pragma unroll
  for (int i = 0; i < 4; i++) {
    int f4 = t + i * 256;
    int nl = f4 >> 5;
    if (base + nl < N) {
      float4 v = ((const float4*)(x + (size_t)base * DIN))[f4];
      int col = (f4 & 31) << 2;
      *((float4*)&xs[nl * 132 + col]) = v;
    }
  }
  __syncthreads();
  int nl = t >> 3, j = t & 7;
  int n0 = base + nl;
  if (n0 >= N) return;
  float acc = b[j];
  const float* xr = &xs[nl * 132];
#pragma unroll 8
  for (int k = 0; k < DIN; k++) acc = fmaf(xr[k], ws_[k * HIDF + j], acc);
  xp[(size_t)n0 * HIDF + j] = acc;
}

// ---------------- per-node attention coefficients, layer 1 (H=2, D=4) ----------------
__global__ __launch_bounds__(256) void k_alpha1(
    const float* __restrict__ xp, int N,
    const float* __restrict__ p0, float* __restrict__ o0,
    const float* __restrict__ p1, float* __restrict__ o1,
    const float* __restrict__ p2, float* __restrict__ o2,
    const float* __restrict__ p3, float* __restrict__ o3)
{
  int n = blockIdx.x * blockDim.x + threadIdx.x;
  if (n >= N) return;
  float4 a4 = ((const float4*)xp)[(size_t)n * 2];
  float4 b4 = ((const float4*)xp)[(size_t)n * 2 + 1];
  float xv[8] = {a4.x, a4.y, a4.z, a4.w, b4.x, b4.y, b4.z, b4.w};
#define DOA(p, o)                                                     \
  if (p) {                                                            \
    float s0 = 0.f, s1 = 0.f;                                         \
    for (int d = 0; d < 4; d++) { s0 += xv[d] * p[d]; s1 += xv[4 + d] * p[4 + d]; } \
    ((float2*)o)[n] = make_float2(s0, s1);                            \
  }
  DOA(p0, o0) DOA(p1, o1) DOA(p2, o2) DOA(p3, o3)
#undef DOA
}

// ---------------- CSR build A: batched LDS count (16-bit packed) + local rank ----------------
__global__ __launch_bounds__(1024) void k_count(
    const int* __restrict__ d0, const int* __restrict__ d1, const int* __restrict__ d2,
    int E, int n0, int n1, int n2, int Gmax, int nc,
    int* __restrict__ P, unsigned short* __restrict__ LR)
{
  int ty = blockIdx.z;
  const int* dst = ty == 0 ? d0 : (ty == 1 ? d1 : d2);
  int Nt = ty == 0 ? n0 : (ty == 1 ? n1 : n2);
  int g = blockIdx.y;
  if (g >= ((Nt + BPG - 1) >> LOGB)) return;
  unsigned short* lrank = LR + (size_t)ty * E;
  __shared__ int lh[W];
  int t = threadIdx.x;
  for (int i = t; i < W; i += 1024) lh[i] = 0;
  __syncthreads();
  int c = blockIdx.x;
  int e0 = c << LOGC;
  int e1 = min(E, e0 + (1 << LOGC));
  for (int q = (e0 >> 2) + t, qe = (e1 + 3) >> 2; q < qe; q += 1024) {
    int base = q << 2;
    int m = min(4, e1 - base);
    int dd[4];
    if (m == 4) {
      int4 v = ((const int4*)dst)[q];
      dd[0] = v.x; dd[1] = v.y; dd[2] = v.z; dd[3] = v.w;
    } else {
      for (int k = 0; k < 4; k++) dd[k] = (k < m) ? dst[base + k] : -1;
    }
#pragma unroll
    for (int k = 0; k < 4; k++) {
      int d = dd[k];
      if (d >= 0 && (d >> LOGB) == g) {
        int sh = (d & 1) << 4;
        int old = atomicAdd(&lh[(d & (BPG - 1)) >> 1], 1 << sh);
        lrank[base + k] = (unsigned short)((old >> sh) & 0xffff);
      }
    }
  }
  __syncthreads();
  int* Pb = P + (((size_t)ty * Gmax + g) * nc + c) * W;
  for (int i = t; i < W; i += 1024) Pb[i] = lh[i];
}

// ---------------- CSR build B: per-bin prefix over chunks (packed, in place) + degree ----------
__global__ __launch_bounds__(256) void k_chunkscan(
    int* __restrict__ P, int* __restrict__ DEGs,
    int n0, int n1, int n2, int nmx, int Gmax, int nc)
{
  int ty = blockIdx.y;
  int Nt = ty == 0 ? n0 : (ty == 1 ? n1 : n2);
  int Gt = (Nt + BPG - 1) >> LOGB;
  int wi = blockIdx.x * 256 + threadIdx.x;
  if (wi >= Gt * W) return;
  int g = wi >> (LOGB - 1);
  int wrd = wi & (W - 1);
  int* base = P + (((size_t)ty * Gmax + g) * nc) * W + wrd;
  int run0 = 0, run1 = 0;
  for (int c = 0; c < nc; c++) {
    int v = base[(size_t)c * W];
    base[(size_t)c * W] = (run0 & 0xffff) | (run1 << 16);
    run0 += v & 0xffff;
    run1 += (v >> 16) & 0xffff;
  }
  int di = (g << LOGB) + (wrd << 1);
  int* deg = DEGs + (size_t)ty * nmx;
  if (di < Nt) deg[di] = run0;
  if (di + 1 < Nt) deg[di + 1] = run1;
}

// ---------------- exclusive scan, batched over 3 types ----------------
__global__ __launch_bounds__(256) void k_scan1(
    const int* __restrict__ DEGs, int n0, int n1, int n2, int nmx, int nmx1,
    int* __restrict__ OFFs, int* __restrict__ BS)
{
  int ty = blockIdx.y;
  int Nt = ty == 0 ? n0 : (ty == 1 ? n1 : n2);
  int nb = (Nt + 255) >> 8;
  if ((int)blockIdx.x >= nb) return;
  const int* deg = DEGs + (size_t)ty * nmx;
  int* off = OFFs + (size_t)ty * nmx1;
  int* bsum = BS + ty * 512;
  int t = threadIdx.x;
  int i = blockIdx.x * 256 + t;
  int v = (i < Nt) ? deg[i] : 0;
  int lane = t & 63, wv = t >> 6;
  int x = v;
#pragma unroll
  for (int o = 1; o < 64; o <<= 1) { int u = __shfl_up(x, o, 64); if (lane >= o) x += u; }
  __shared__ int ws[4];
  if (lane == 63) ws[wv] = x;
  __syncthreads();
  if (t == 0) { int s = 0; for (int k = 0; k < 4; k++) { int tmp = ws[k]; ws[k] = s; s += tmp; } }
  __syncthreads();
  int excl = x - v + ws[wv];
  if (i < Nt) off[i] = excl;
  if (t == 255) bsum[blockIdx.x] = excl + v;
}

__global__ __launch_bounds__(256) void k_scan2(int* __restrict__ BS,
                                               int n0, int n1, int n2)
{
  int ty = blockIdx.y;
  int Nt = ty == 0 ? n0 : (ty == 1 ? n1 : n2);
  int nb = (Nt + 255) >> 8;
  int* b = BS + ty * 512;
  __shared__ int ws[4];
  __shared__ int carry;
  int t = threadIdx.x, lane = t & 63, wv = t >> 6;
  if (t == 0) carry = 0;
  __syncthreads();
  for (int base = 0; base < nb; base += 256) {
    int i = base + t;
    int v = (i < nb) ? b[i] : 0;
    int x = v;
#pragma unroll
    for (int o = 1; o < 64; o <<= 1) { int u = __shfl_up(x, o, 64); if (lane >= o) x += u; }
    if (lane == 63) ws[wv] = x;
    __syncthreads();
    if (t == 0) { int s = 0; for (int k = 0; k < 4; k++) { int tmp = ws[k]; ws[k] = s; s += tmp; } }
    __syncthreads();
    int excl = x - v + ws[wv] + carry;
    if (i < nb) b[i] = excl;
    __syncthreads();
    if (t == 255) carry = excl + v;
    __syncthreads();
  }
}

__global__ __launch_bounds__(256) void k_scan3(
    int* __restrict__ OFFs, const int* __restrict__ BS,
    int n0, int n1, int n2, int nmx1, int E)
{
  int ty = blockIdx.y;
  int Nt = ty == 0 ? n0 : (ty == 1 ? n1 : n2);
  int nb = (Nt + 255) >> 8;
  if ((int)blockIdx.x >= nb) return;
  int* off = OFFs + (size_t)ty * nmx1;
  const int* bsum = BS + ty * 512;
  int i = blockIdx.x * 256 + threadIdx.x;
  if (i < Nt) off[i] += bsum[blockIdx.x];
  if (i == 0) off[Nt] = E;
}

// ---------------- CSR build C: batched edge-parallel placement (no atomics) ----------------
__global__ __launch_bounds__(256) void k_place(
    const int* __restrict__ s0, const int* __restrict__ s1, const int* __restrict__ s2,
    int E, int nmx1, int Gmax, int nc,
    const unsigned short* __restrict__ LR, const int* __restrict__ OFFs,
    const int* __restrict__ P,
    int* __restrict__ c0, int* __restrict__ c1, int* __restrict__ c2)
{
  int ty = blockIdx.y;
  const int* src = ty == 0 ? s0 : (ty == 1 ? s1 : s2);
  const int* dst = src + E;
  int* csr = ty == 0 ? c0 : (ty == 1 ? c1 : c2);
  const int* off = OFFs + (size_t)ty * nmx1;
  const unsigned short* lrank = LR + (size_t)ty * E;
  int q = blockIdx.x * 256 + threadIdx.x;
  int base = q << 2;
  if (base >= E) return;
  int c = base >> LOGC;
  if (base + 4 <= E) {
    int4 sv = ((const int4*)src)[q];
    int4 dv = ((const int4*)dst)[q];
    ushort4 lv = ((const ushort4*)lrank)[q];
    int ss[4] = {sv.x, sv.y, sv.z, sv.w};
    int dd[4] = {dv.x, dv.y, dv.z, dv.w};
    unsigned short ll[4] = {lv.x, lv.y, lv.z, lv.w};
#pragma unroll
    for (int k = 0; k < 4; k++) {
      int d = dd[k], g = d >> LOGB, b = d & (BPG - 1);
      int wv = P[(((size_t)ty * Gmax + g) * nc + c) * W + (b >> 1)];
      int pref = (wv >> ((d & 1) << 4)) & 0xffff;
      csr[off[d] + pref + ll[k]] = ss[k];
    }
  } else {
    for (int k = 0; k < E - base; k++) {
      int d = dst[base + k], g = d >> LOGB, b = d & (BPG - 1);
      int wv = P[(((size_t)ty * Gmax + g) * nc + c) * W + (b >> 1)];
      int pref = (wv >> ((d & 1) << 4)) & 0xffff;
      csr[off[d] + pref + lrank[base + k]] = src[base + k];
    }
  }
}

// ---------------- gather, layer 1 (H=2,D=4): batched 3 types, 16 lanes/dst ----------------
__global__ __launch_bounds__(256) void k_gather1(
    const int* __restrict__ c0, const int* __restrict__ c1, const int* __restrict__ c2,
    const int* __restrict__ OFFs, int nmx1,
    const float* __restrict__ as0, const float* __restrict__ ad0,
    const float* __restrict__ x0, float* __restrict__ o0, int n0,
    const float* __restrict__ as1, const float* __restrict__ ad1,
    const float* __restrict__ x1, float* __restrict__ o1, int n1,
    const float* __restrict__ as2, const float* __restrict__ ad2,
    const float* __restrict__ x2, float* __restrict__ o2, int n2)
{
  int ty = blockIdx.y;
  const int* csr = ty == 0 ? c0 : (ty == 1 ? c1 : c2);
  const float* as_ = ty == 0 ? as0 : (ty == 1 ? as1 : as2);
  const float* ad_ = ty == 0 ? ad0 : (ty == 1 ? ad1 : ad2);
  const float* xps = ty == 0 ? x0 : (ty == 1 ? x1 : x2);
  float* out = ty == 0 ? o0 : (ty == 1 ? o1 : o2);
  int Nt = ty == 0 ? n0 : (ty == 1 ? n1 : n2);
  const int* off = OFFs + (size_t)ty * nmx1;
  int t = blockIdx.x * 256 + threadIdx.x;
  int d = t >> 4, l = t & 15;
  if (d >= Nt) return;
  int i0 = off[d], i1 = off[d + 1];
  float2 adv = ((const float2*)ad_)[d];
  float s0 = 0.f, s1 = 0.f;
  float acc[8] = {0.f, 0.f, 0.f, 0.f, 0.f, 0.f, 0.f, 0.f};
  for (int i = i0 + l; i < i1; i += 16) {
    int s = csr[i];
    float2 av = ((const float2*)as_)[s];
    float a0 = av.x + adv.x; a0 = a0 > 0.f ? a0 : 0.2f * a0;
    float a1 = av.y + adv.y; a1 = a1 > 0.f ? a1 : 0.2f * a1;
    float e0 = __expf(a0), e1 = __expf(a1);
    s0 += e0; s1 += e1;
    float4 xa = ((const float4*)xps)[(size_t)s * 2];
    float4 xb = ((const float4*)xps)[(size_t)s * 2 + 1];
    acc[0] += e0 * xa.x; acc[1] += e0 * xa.y; acc[2] += e0 * xa.z; acc[3] += e0 * xa.w;
    acc[4] += e1 * xb.x; acc[5] += e1 * xb.y; acc[6] += e1 * xb.z; acc[7] += e1 * xb.w;
  }
#pragma unroll
  for (int m = 1; m < 16; m <<= 1) {
    s0 += __shfl_xor(s0, m, 16);
    s1 += __shfl_xor(s1, m, 16);
#pragma unroll
    for (int k = 0; k < 8; k++) acc[k] += __shfl_xor(acc[k], m, 16);
  }
  if (l) return;
  float r0 = 1.f / (s0 + 1e-16f), r1 = 1.f / (s1 + 1e-16f);
  float4 q0 = make_float4(fmaxf(acc[0] * r0, 0.f), fmaxf(acc[1] * r0, 0.f),
                          fmaxf(acc[2] * r0, 0.f), fmaxf(acc[3] * r0, 0.f));
  float4 q1 = make_float4(fmaxf(acc[4] * r1, 0.f), fmaxf(acc[5] * r1, 0.f),
                          fmaxf(acc[6] * r1, 0.f), fmaxf(acc[7] * r1, 0.f));
  ((float4*)out)[(size_t)d * 2] = q0;
  ((float4*)out)[(size_t)d * 2 + 1] = q1;
}

// ---------------- gather, layer 2 (H=1,F=7): batched 2 types, 16 lanes/dst ----------------
__global__ __launch_bounds__(256) void k_gather2(
    const int* __restrict__ c0, const int* __restrict__ c1,
    const int* __restrict__ off0, const int* __restrict__ off1,
    const float* __restrict__ as0, const float* __restrict__ ad0,
    const float* __restrict__ x0, float* __restrict__ o0,
    const float* __restrict__ as1, const float* __restrict__ ad1,
    const float* __restrict__ x1, float* __restrict__ o1, int N)
{
  int ty = blockIdx.y;
  const int* csr = ty == 0 ? c0 : c1;
  const int* off = ty == 0 ? off0 : off1;
  const float* as_ = ty == 0 ? as0 : as1;
  const float* ad_ = ty == 0 ? ad0 : ad1;
  const float* xps = ty == 0 ? x0 : x1;
  float* out = ty == 0 ? o0 : o1;
  int t = blockIdx.x * 256 + threadIdx.x;
  int d = t >> 4, l = t & 15;
  if (d >= N) return;
  int i0 = off[d], i1 = off[d + 1];
  float adv = ad_[d];
  float ssum = 0.f;
  float acc[7] = {0.f, 0.f, 0.f, 0.f, 0.f, 0.f, 0.f};
  for (int i = i0 + l; i < i1; i += 16) {
    int s = csr[i];
    float a = as_[s] + adv; a = a > 0.f ? a : 0.2f * a;
    float ex = __expf(a);
    ssum += ex;
    float4 xa = ((const float4*)xps)[(size_t)s * 2];
    float4 xb = ((const float4*)xps)[(size_t)s * 2 + 1];
    acc[0] += ex * xa.x; acc[1] += ex * xa.y; acc[2] += ex * xa.z; acc[3] += ex * xa.w;
    acc[4] += ex * xb.x; acc[5] += ex * xb.y; acc[6] += ex * xb.z;
  }
#pragma unroll
  for (int m = 1; m < 16; m <<= 1) {
    ssum += __shfl_xor(ssum, m, 16);
#pragma unroll
    for (int k = 0; k < 7; k++) acc[k] += __shfl_xor(acc[k], m, 16);
  }
  if (l) return;
  float r = 1.f / (ssum + 1e-16f);
  float4 q0 = make_float4(fmaxf(acc[0] * r, 0.f), fmaxf(acc[1] * r, 0.f),
                          fmaxf(acc[2] * r, 0.f), fmaxf(acc[3] * r, 0.f));
  float4 q1 = make_float4(fmaxf(acc[4] * r, 0.f), fmaxf(acc[5] * r, 0.f),
                          fmaxf(acc[6] * r, 0.f), 0.f);
  ((float4*)out)[(size_t)d * 2] = q0;
  ((float4*)out)[(size_t)d * 2 + 1] = q1;
}

// ---------------- semantic-attention reduction ----------------
__global__ __launch_bounds__(256) void k_red(
    const float* __restrict__ h, int N, int F,
    const float* __restrict__ kw, const float* __restrict__ kb,
    float* __restrict__ red)
{
  __shared__ float kws[64], kbs[8];
  __shared__ float sm[256 * 8];
  int t = threadIdx.x;
  if (t < F * F) kws[t] = kw[t];
  if (t < F) kbs[t] = kb[t];
  __syncthreads();
  float acc[8] = {0, 0, 0, 0, 0, 0, 0, 0};
  for (int n = blockIdx.x * 256 + t; n < N; n += gridDim.x * 256) {
    const float* row = h + (size_t)n * 8;
    float xv[8];
    for (int k = 0; k < F; k++) xv[k] = row[k];
    for (int f = 0; f < F; f++) {
      float s = kbs[f];
      for (int k = 0; k < F; k++) s += xv[k] * kws[k * F + f];
      acc[f] += tanhf(s);
    }
  }
  for (int f = 0; f < 8; f++) sm[t * 8 + f] = (f < F) ? acc[f] : 0.f;
  __syncthreads();
  for (int s2 = 128; s2 > 0; s2 >>= 1) {
    if (t < s2)
      for (int f = 0; f < 8; f++) sm[t * 8 + f] += sm[(t + s2) * 8 + f];
    __syncthreads();
  }
  if (t < F) atomicAdd(&red[t], sm[t]);
}

// ---------------- semantic attention weights (tiny) ----------------
__global__ void k_attn(const float* __restrict__ red, const float* __restrict__ q,
                       int T, int F, float invN, float* __restrict__ attn)
{
  if (threadIdx.x != 0 || blockIdx.x != 0) return;
  float v[4]; float m = -1e30f;
  for (int t2 = 0; t2 < T; t2++) {
    float s = 0.f;
    for (int f = 0; f < F; f++) s += q[f] * red[t2 * F + f];
    s *= invN;
    v[t2] = s; m = fmaxf(m, s);
  }
  float sum = 0.f;
  for (int t2 = 0; t2 < T; t2++) { v[t2] = __expf(v[t2] - m); sum += v[t2]; }
  for (int t2 = 0; t2 < T; t2++) attn[t2] = v[t2] / sum;
}

// ---------- layer-2 projection with fused semantic combine (+relu) + fused alpha2 ----------
__global__ __launch_bounds__(256) void k_proj2(
    const float* __restrict__ h0, const float* __restrict__ h1,
    const float* __restrict__ attn, int N,
    const float* __restrict__ w, const float* __restrict__ b,
    float* __restrict__ xp2,
    const float* __restrict__ pa0, float* __restrict__ oa0,
    const float* __restrict__ pa1, float* __restrict__ oa1,
    const float* __restrict__ pa2, float* __restrict__ oa2)
{
  int n = blockIdx.x * blockDim.x + threadIdx.x;
  if (n >= N) return;
  float a0 = 1.f, a1 = 0.f;
  if (attn) { a0 = attn[0]; a1 = attn[1]; }
  float4 u0 = ((const float4*)h0)[(size_t)n * 2];
  float4 u1 = ((const float4*)h0)[(size_t)n * 2 + 1];
  float xv[8] = {u0.x, u0.y, u0.z, u0.w, u1.x, u1.y, u1.z, u1.w};
  if (h1) {
    float4 v0 = ((const float4*)h1)[(size_t)n * 2];
    float4 v1 = ((const float4*)h1)[(size_t)n * 2 + 1];
    float yv[8] = {v0.x, v0.y, v0.z, v0.w, v1.x, v1.y, v1.z, v1.w};
    for (int j = 0; j < 8; j++) xv[j] = a0 * xv[j] + a1 * yv[j];
  }
  for (int j = 0; j < 8; j++) xv[j] = fmaxf(xv[j], 0.f);
  float y[7];
  for (int j = 0; j < 7; j++) y[j] = b[j];
  for (int k = 0; k < 8; k++) {
    float xk = xv[k];
    for (int j = 0; j < 7; j++) y[j] += xk * w[k * 7 + j];
  }
  ((float4*)xp2)[(size_t)n * 2] = make_float4(y[0], y[1], y[2], y[3]);
  ((float4*)xp2)[(size_t)n * 2 + 1] = make_float4(y[4], y[5], y[6], 0.f);
#define DOA2(p, o)                                      \
  if (p) {                                              \
    float s = 0.f;                                      \
    for (int j = 0; j < 7; j++) s += y[j] * p[j];       \
    o[n] = s;                                           \
  }
  DOA2(pa0, oa0) DOA2(pa1, oa1) DOA2(pa2, oa2)
#undef DOA2
}

// ---------------- final combine + log_softmax ----------------
__global__ __launch_bounds__(256) void k_final(
    const float* __restrict__ h0, const float* __restrict__ h1,
    const float* __restrict__ attn, float* __restrict__ out, int N)
{
  int n = blockIdx.x * blockDim.x + threadIdx.x;
  if (n >= N) return;
  float a0 = attn[0], a1 = attn[1];
  const float* r0 = h0 + (size_t)n * 8;
  const float* r1 = h1 + (size_t)n * 8;
  float v[7]; float m = -1e30f;
  for (int c = 0; c < 7; c++) { float t = a0 * r0[c] + a1 * r1[c]; v[c] = t; m = fmaxf(m, t); }
  float sum = 0.f;
  for (int c = 0; c < 7; c++) sum += __expf(v[c] - m);
  float lse = m + logf(sum);
  for (int c = 0; c < 7; c++) out[(size_t)n * 7 + c] = v[c] - lse;
}

extern "C" void kernel_launch(void* const* d_in, const int* in_sizes, int n_in,
                              void* d_out, int out_size, void* d_ws, size_t ws_size,
                              hipStream_t stream)
{
  const float* x_p  = (const float*)d_in[0];
  const float* x_a  = (const float*)d_in[1];
  const int*   eipp = (const int*)d_in[2];
  const int*   eipa = (const int*)d_in[3];
  const int*   eiap = (const int*)d_in[4];
  const float* w1p  = (const float*)d_in[5];
  const float* b1p  = (const float*)d_in[6];
  const float* w1a  = (const float*)d_in[7];
  const float* b1a  = (const float*)d_in[8];
  const float* as1pp = (const float*)d_in[9];
  const float* ad1pp = (const float*)d_in[10];
  const float* as1pa = (const float*)d_in[11];
  const float* ad1pa = (const float*)d_in[12];
  const float* as1ap = (const float*)d_in[13];
  const float* ad1ap = (const float*)d_in[14];
  const float* kw1 = (const float*)d_in[15];
  const float* kb1 = (const float*)d_in[16];
  const float* q1  = (const float*)d_in[17];
  const float* w2p = (const float*)d_in[18];
  const float* b2p = (const float*)d_in[19];
  const float* w2a = (const float*)d_in[20];
  const float* b2a = (const float*)d_in[21];
  const float* as2pp = (const float*)d_in[22];
  const float* ad2pp = (const float*)d_in[23];
  // d_in[24]=as2pa, d_in[25]=ad2pa unused: pa edges only feed author nodes,
  // and author layer-2 output is dead (final output is papers only).
  const float* as2ap = (const float*)d_in[26];
  const float* ad2ap = (const float*)d_in[27];
  const float* kw2 = (const float*)d_in[28];
  const float* kb2 = (const float*)d_in[29];
  const float* q2  = (const float*)d_in[30];

  const int NP = in_sizes[0] / DIN;
  const int NA = in_sizes[1] / DIN;
  const int E  = in_sizes[2] / 2;
  (void)n_in; (void)out_size; (void)ws_size;

  const int nc   = (E + (1 << LOGC) - 1) >> LOGC;
  const int nmx  = NP > NA ? NP : NA;
  const int nmx1 = nmx + 1;
  const int GP = (NP + BPG - 1) >> LOGB;
  const int GA = (NA + BPG - 1) >> LOGB;
  const int Gmax = GP > GA ? GP : GA;

  float* w = (float*)d_ws;
  size_t off_ = 0;
  auto A = [&](size_t n) { float* p = w + off_; off_ += (n + 3) & ~(size_t)3; return p; };
  float* XP_P1 = A((size_t)NP * 8);   // reused as XP2_P
  float* XP_A1 = A((size_t)NA * 8);   // reused as XP2_A
  float* AS_PP = A((size_t)NP * 2);   // reused as A2SPP
  float* AD_PP = A((size_t)NP * 2);   // reused as A2DPP
  float* AS_PA = A((size_t)NP * 2);   // reused as A2DAP
  float* AD_PA = A((size_t)NA * 2);   // reused as A2SAP
  float* AS_AP = A((size_t)NA * 2);
  float* AD_AP = A((size_t)NP * 2);
  float* O_PP  = A((size_t)NP * 8);   // reused as O2PP
  float* O_PA  = A((size_t)NA * 8);
  float* O_AP  = A((size_t)NP * 8);   // reused as O2AP
  float* ATT1  = A(2);
  float* ATT2  = A(2);
  float* RED1  = A(16);
  float* RED2  = A(16);
  int* CSR_PP = (int*)A((size_t)E);
  int* CSR_PA = (int*)A((size_t)E);
  int* CSR_AP = (int*)A((size_t)E);
  int* OFFs   = (int*)A((size_t)3 * nmx1);
  int* BSUM   = (int*)A(3 * 512);
  unsigned short* LR = (unsigned short*)A(((size_t)3 * E) / 2);
  int* DEGs   = (int*)A((size_t)3 * nmx);
  int* PBUF   = (int*)A((size_t)3 * Gmax * nc * W);

  float* XP2_P = XP_P1;
  float* XP2_A = XP_A1;
  float* A2SPP = AS_PP;
  float* A2DPP = AD_PP;
  float* A2DAP = AS_PA;
  float* A2SAP = AD_PA;
  float* O2PP  = O_PP;
  float* O2AP  = O_AP;

  hipMemsetAsync(RED1, 0, 32 * sizeof(float), stream);  // RED1+RED2 contiguous

  dim3 B(256);
  int nbP = (NP + 255) / 256, nbA = (NA + 255) / 256;
  int nbmax = (nmx + 255) / 256;
  int gG = (nmx * 16 + 255) / 256;

  // layer 1 projections + per-node alphas
  k_proj1<<<(NP + 31) / 32, B, 0, stream>>>(x_p, w1p, b1p, XP_P1, NP);
  k_proj1<<<(NA + 31) / 32, B, 0, stream>>>(x_a, w1a, b1a, XP_A1, NA);
  k_alpha1<<<nbP, B, 0, stream>>>(XP_P1, NP,
      as1pp, AS_PP, ad1pp, AD_PP, as1pa, AS_PA, ad1ap, AD_AP);
  k_alpha1<<<nbA, B, 0, stream>>>(XP_A1, NA,
      ad1pa, AD_PA, as1ap, AS_AP, nullptr, nullptr, nullptr, nullptr);

  // batched CSR build for all 3 edge types (type order: pp, pa, ap)
  const int* d_pp = eipp + E; const int* d_pa = eipa + E; const int* d_ap = eiap + E;
  k_count<<<dim3(nc, Gmax, 3), dim3(1024), 0, stream>>>(
      d_pp, d_pa, d_ap, E, NP, NA, NP, Gmax, nc, PBUF, LR);
  k_chunkscan<<<dim3((Gmax * W + 255) / 256, 3), B, 0, stream>>>(
      PBUF, DEGs, NP, NA, NP, nmx, Gmax, nc);
  k_scan1<<<dim3(nbmax, 3), B, 0, stream>>>(DEGs, NP, NA, NP, nmx, nmx1, OFFs, BSUM);
  k_scan2<<<dim3(1, 3), B, 0, stream>>>(BSUM, NP, NA, NP);
  k_scan3<<<dim3(nbmax, 3), B, 0, stream>>>(OFFs, BSUM, NP, NA, NP, nmx1, E);
  k_place<<<dim3((E / 4 + 255) / 256, 3), B, 0, stream>>>(
      eipp, eipa, eiap, E, nmx1, Gmax, nc, LR, OFFs, PBUF, CSR_PP, CSR_PA, CSR_AP);

  // batched layer-1 gathers
  k_gather1<<<dim3(gG, 3), B, 0, stream>>>(
      CSR_PP, CSR_PA, CSR_AP, OFFs, nmx1,
      AS_PP, AD_PP, XP_P1, O_PP, NP,
      AS_PA, AD_PA, XP_P1, O_PA, NA,
      AS_AP, AD_AP, XP_A1, O_AP, NP);

  // layer 1 semantic attention (paper: T=2; author: T=1 -> O_PA passes through)
  k_red<<<256, B, 0, stream>>>(O_PP, NP, 8, kw1, kb1, RED1);
  k_red<<<256, B, 0, stream>>>(O_AP, NP, 8, kw1, kb1, RED1 + 8);
  k_attn<<<1, 1, 0, stream>>>(RED1, q1, 2, 8, 1.0f / NP, ATT1);

  // layer 2 projections (paper: fused semantic combine; author: passthrough) + alphas
  k_proj2<<<nbP, B, 0, stream>>>(O_PP, O_AP, ATT1, NP, w2p, b2p, XP2_P,
      as2pp, A2SPP, ad2pp, A2DPP, ad2ap, A2DAP);
  k_proj2<<<nbA, B, 0, stream>>>(O_PA, nullptr, nullptr, NA, w2a, b2a, XP2_A,
      as2ap, A2SAP, nullptr, nullptr, nullptr, nullptr);

  // batched layer-2 gathers (pp and ap; author layer-2 output is dead)
  int off_ap_idx = 2;  // OFFs stride: type order pp=0, pa=1, ap=2
  k_gather2<<<dim3((NP * 16 + 255) / 256, 2), B, 0, stream>>>(
      CSR_PP, CSR_AP, OFFs, OFFs + (size_t)off_ap_idx * nmx1,
      A2SPP, A2DPP, XP2_P, O2PP,
      A2SAP, A2DAP, XP2_A, O2AP, NP);

  // layer 2 semantic attention + final log_softmax
  k_red<<<256, B, 0, stream>>>(O2PP, NP, 7, kw2, kb2, RED2);
  k_red<<<256, B, 0, stream>>>(O2AP, NP, 7, kw2, kb2, RED2 + 7);
  k_attn<<<1, 1, 0, stream>>>(RED2, q2, 2, 7, 1.0f / NP, ATT2);
  k_final<<<nbP, B, 0, stream>>>(O2PP, O2AP, ATT2, (float*)d_out, NP);
}